// Round 18
// baseline (69.449 us; speedup 1.0000x reference)
//
#include <hip/hip_runtime.h>

#define BSZ 4096
#define D 1024
#define N2 8192
#define TEMPV 0.5f
// exp(x/T) = exp2(x * log2(e)/T)
#define EXPSCALE 2.8853900817779268f
#define NTB 32      // 8192 / 256 tiles per dim

typedef __attribute__((ext_vector_type(4))) float f32x4;
typedef __attribute__((ext_vector_type(4))) int i32x4;
typedef __attribute__((ext_vector_type(8))) int i32x8;

// bit-exact float -> OCP e4m3fn, RNE (inputs |x|<=1 here; clamp kept for safety)
__device__ inline unsigned int f2e4m3(float x) {
  unsigned int u = __float_as_uint(x);
  const unsigned int s = (u >> 24) & 0x80u;
  u &= 0x7fffffffu;
  const float a = __uint_as_float(u);
  if (a >= 448.0f) return s | 0x7Eu;
  if (a < 0.015625f) {                       // < 2^-6: subnormal
    const int m = (int)rintf(a * 512.0f);    // RNE; 8 -> 0x08 == 2^-6 exactly
    return s | (unsigned int)m;
  }
  u += 0x7FFFFu + ((u >> 20) & 1u);          // RNE to 3 mantissa bits
  const unsigned int e = u >> 23;            // biased f32 exp (>=121)
  const unsigned int m3 = (u >> 20) & 7u;
  return s | (((e - 120u) << 3) | m3);       // e4m3 bias 7
}

__device__ inline void gload16(const void* g, void* l) {
  __builtin_amdgcn_global_load_lds(
      (const __attribute__((address_space(1))) void*)g,
      (__attribute__((address_space(3))) void*)l, 16, 0, 0);
}

// ---------------- Kernel A: L2-normalize rows (R15 layout), emit fp8 reps + pos ---------
__global__ __launch_bounds__(256) void knorm(const float* __restrict__ ei,
                                             const float* __restrict__ ej,
                                             unsigned char* __restrict__ reps8,
                                             float* __restrict__ pos,
                                             int* __restrict__ cnt) {
  const int r = blockIdx.x;
  const int t = threadIdx.x;
  if (r == 0 && t == 0) *cnt = 0;   // reset done-counter for fused kred (each call)
  const float4 vi = ((const float4*)(ei + (size_t)r * D))[t];
  const float4 vj = ((const float4*)(ej + (size_t)r * D))[t];
  float ssi = vi.x * vi.x + vi.y * vi.y + vi.z * vi.z + vi.w * vi.w;
  float ssj = vj.x * vj.x + vj.y * vj.y + vj.z * vj.z + vj.w * vj.w;
  float sij = vi.x * vj.x + vi.y * vj.y + vi.z * vj.z + vi.w * vj.w;
#pragma unroll
  for (int o = 32; o > 0; o >>= 1) {
    ssi += __shfl_xor(ssi, o);
    ssj += __shfl_xor(ssj, o);
    sij += __shfl_xor(sij, o);
  }
  __shared__ float red[12];
  const int lane = t & 63, wid = t >> 6;
  if (lane == 0) { red[wid * 3] = ssi; red[wid * 3 + 1] = ssj; red[wid * 3 + 2] = sij; }
  __syncthreads();
  ssi = red[0] + red[3] + red[6] + red[9];
  ssj = red[1] + red[4] + red[7] + red[10];
  sij = red[2] + red[5] + red[8] + red[11];
  const float inv_i = rsqrtf(fmaxf(ssi, 1e-24f));
  const float inv_j = rsqrtf(fmaxf(ssj, 1e-24f));
  const float xi0 = vi.x * inv_i, xi1 = vi.y * inv_i, xi2 = vi.z * inv_i, xi3 = vi.w * inv_i;
  const float xj0 = vj.x * inv_j, xj1 = vj.y * inv_j, xj2 = vj.z * inv_j, xj3 = vj.w * inv_j;
  const unsigned int pi = f2e4m3(xi0) | (f2e4m3(xi1) << 8) | (f2e4m3(xi2) << 16) | (f2e4m3(xi3) << 24);
  const unsigned int pj = f2e4m3(xj0) | (f2e4m3(xj1) << 8) | (f2e4m3(xj2) << 16) | (f2e4m3(xj3) << 24);
  *(unsigned int*)(reps8 + (size_t)r * 1024 + t * 4) = pi;
  *(unsigned int*)(reps8 + (size_t)(BSZ + r) * 1024 + t * 4) = pj;
  if (t == 0) pos[r] = sij * inv_i * inv_j;
}

// ======================= shared asm helpers =======================
#define BARRIER() do { __builtin_amdgcn_s_barrier(); asm volatile("" ::: "memory"); } while (0)
#define STR2(x) #x
#define WAITV(n) asm volatile("s_waitcnt vmcnt(" STR2(n) ")" ::: "memory")
#define LGKM0() asm volatile("s_waitcnt lgkmcnt(0)" ::: "memory")

// ---------------- Kernel B (merged): tails FIRST (0..127), mains (128..639) -------------
// Main: 256x256 MX-fp8 tile (unit scales), BK=128, 8 waves (2Mx4N), wave tile 128x64,
// LDS 128 KiB (A dbuf @0/@16384, B dbuf @32768/@49152), fully unrolled 8 K-tiles.
// R18: A-staging moved to ph4 with distance ~1.7 tiles — SG_A(t+2) issues at tile t ph4
// (ABUF(t&1) free: last read = ph3 Aq3, ph3-end barrier separates). Ledger: prologue
// stages B(0),A(0),B(1),A(1), WAITV(8); steady ph3-wait outstanding = B(t+1)+A(t+1)+
// B(t+2) = 12 -> WAITV(4) retires A(t+1)+B(t+1) for ph4's next-buffer reads; t6 WAITV(0).
#define SG_A(ii, ktv, dst) gload16(reps8 + (size_t)(arow0 + (ii) * 64 + (t >> 3)) * 1024 + \
                                       (ktv) * 128 + (((t & 7) ^ ((t >> 3) & 7)) << 4),    \
                                   (dst) + (size_t)(ii) * 8192 + (size_t)t * 16)
#define SG_B(ii, ktv, dst) gload16(reps8 + (size_t)(brow0 + (ii) * 64 + (t >> 3)) * 1024 + \
                                       (ktv) * 128 + (((t & 7) ^ ((t >> 3) & 7)) << 4),    \
                                   (dst) + (size_t)(ii) * 8192 + (size_t)t * 16)

#define ABUF(c) ((c) ? 16384 : 0)
#define BBUF(c) ((c) ? 49152 : 32768)

#define READ_A2(bufoff, p) do {                                                       \
    i32x4 a0l = *(const i32x4*)(smem + (bufoff) + ((p) * 2) * 2048 + aaddr0);         \
    i32x4 a0h = *(const i32x4*)(smem + (bufoff) + ((p) * 2) * 2048 + aaddr1);         \
    i32x4 a1l = *(const i32x4*)(smem + (bufoff) + ((p) * 2 + 1) * 2048 + aaddr0);     \
    i32x4 a1h = *(const i32x4*)(smem + (bufoff) + ((p) * 2 + 1) * 2048 + aaddr1);     \
    afp[0] = __builtin_shufflevector(a0l, a0h, 0, 1, 2, 3, 4, 5, 6, 7);               \
    afp[1] = __builtin_shufflevector(a1l, a1h, 0, 1, 2, 3, 4, 5, 6, 7);               \
  } while (0)

#define READ_B2(bufoff, n) do {                                                       \
    i32x4 bl = *(const i32x4*)(smem + (bufoff) + (n) * 2048 + baddr0);                \
    i32x4 bh = *(const i32x4*)(smem + (bufoff) + (n) * 2048 + baddr1);                \
    bfp[n] = __builtin_shufflevector(bl, bh, 0, 1, 2, 3, 4, 5, 6, 7);                 \
  } while (0)

#define MFMA_P(p)                                                       \
  __builtin_amdgcn_s_setprio(1);                                        \
  _Pragma("unroll") for (int nh = 0; nh < 2; nh++)                      \
  _Pragma("unroll") for (int m2 = 0; m2 < 2; m2++)                      \
  _Pragma("unroll") for (int nn = 0; nn < 2; nn++) {                    \
    const int n_ = nh * 2 + nn;                                         \
    acc[2 * (p) + m2][n_] = __builtin_amdgcn_mfma_scale_f32_16x16x128_f8f6f4( \
        afp[m2], bfp[n_], acc[2 * (p) + m2][n_],                        \
        0, 0, 0, 0x7F7F7F7F, 0, 0x7F7F7F7F);                            \
  }                                                                     \
  __builtin_amdgcn_s_setprio(0);

#define DO_TILE(ktv, SA, SB, RDN, HASW, WV)                             \
  {                                                                     \
    READ_B2(BBUF((ktv) & 1), 2); READ_B2(BBUF((ktv) & 1), 3);           \
    MFMA_P(0);                                                          \
    READ_A2(ABUF((ktv) & 1), 1);                                        \
    BARRIER();   /* current-B reads complete before ph3 SG_B */         \
    MFMA_P(1);                                                          \
    READ_A2(ABUF((ktv) & 1), 2);                                        \
    MFMA_P(2);                                                          \
    READ_A2(ABUF((ktv) & 1), 3);                                        \
    if (SB) { SG_B(0, (ktv) + 2, smem + BBUF((ktv) & 1));               \
              SG_B(1, (ktv) + 2, smem + BBUF((ktv) & 1));               \
              SG_B(2, (ktv) + 2, smem + BBUF((ktv) & 1));               \
              SG_B(3, (ktv) + 2, smem + BBUF((ktv) & 1)); }             \
    if (HASW) { WAITV(WV); }                                            \
    BARRIER();   /* staged data visible; A(t)-buffer reads all done */  \
    if (SA) { SG_A(0, (ktv) + 2, smem + ABUF((ktv) & 1));               \
              SG_A(1, (ktv) + 2, smem + ABUF((ktv) & 1));               \
              SG_A(2, (ktv) + 2, smem + ABUF((ktv) & 1));               \
              SG_A(3, (ktv) + 2, smem + ABUF((ktv) & 1)); }             \
    MFMA_P(3);                                                          \
    if (RDN) { READ_A2(ABUF(((ktv) + 1) & 1), 0);                       \
               READ_B2(BBUF(((ktv) + 1) & 1), 0);                       \
               READ_B2(BBUF(((ktv) + 1) & 1), 1); }                     \
  }

// -------- tail-path macros (MX-fp8, 64x128 tile, BK=128) --------
#define UABUF(c) ((c) ? 8192 : 0)
#define UBBUF(c) ((c) ? 32768 : 16384)

#define USG_A(ktv, dstoff) gload16(reps8 + (size_t)(uarow0 + (t >> 3)) * 1024 + \
                                       (ktv) * 128 + (((t & 7) ^ ((t >> 3) & 7)) << 4), \
                                   smem + (dstoff) + (size_t)t * 16)
#define USG_B(ii, ktv, dstoff) gload16(reps8 + (size_t)(ubrow0 + (ii) * 64 + (t >> 3)) * 1024 + \
                                       (ktv) * 128 + (((t & 7) ^ ((t >> 3) & 7)) << 4), \
                                   smem + (dstoff) + (size_t)(ii) * 8192 + (size_t)t * 16)

#define UREAD_A(bufoff) do {                                                          \
    i32x4 a0l = *(const i32x4*)(smem + (bufoff) + uarow * 128 + off0);                \
    i32x4 a0h = *(const i32x4*)(smem + (bufoff) + uarow * 128 + off1);                \
    i32x4 a1l = *(const i32x4*)(smem + (bufoff) + (uarow + 16) * 128 + off0);         \
    i32x4 a1h = *(const i32x4*)(smem + (bufoff) + (uarow + 16) * 128 + off1);         \
    ua[0] = __builtin_shufflevector(a0l, a0h, 0, 1, 2, 3, 4, 5, 6, 7);                \
    ua[1] = __builtin_shufflevector(a1l, a1h, 0, 1, 2, 3, 4, 5, 6, 7);                \
  } while (0)

#define UREAD_B(bufoff) do {                                                          \
    i32x4 b0l = *(const i32x4*)(smem + (bufoff) + ubrow * 128 + off0);                \
    i32x4 b0h = *(const i32x4*)(smem + (bufoff) + ubrow * 128 + off1);                \
    i32x4 b1l = *(const i32x4*)(smem + (bufoff) + (ubrow + 16) * 128 + off0);         \
    i32x4 b1h = *(const i32x4*)(smem + (bufoff) + (ubrow + 16) * 128 + off1);         \
    ub[0] = __builtin_shufflevector(b0l, b0h, 0, 1, 2, 3, 4, 5, 6, 7);                \
    ub[1] = __builtin_shufflevector(b1l, b1h, 0, 1, 2, 3, 4, 5, 6, 7);                \
  } while (0)

#define UMFMA(n)                                                        \
  __builtin_amdgcn_s_setprio(1);                                        \
  _Pragma("unroll") for (int m2 = 0; m2 < 2; m2++)                      \
    uacc[m2][n] = __builtin_amdgcn_mfma_scale_f32_16x16x128_f8f6f4(     \
        ua[m2], ub[n], uacc[m2][n], 0, 0, 0, 0x7F7F7F7F, 0, 0x7F7F7F7F);\
  __builtin_amdgcn_s_setprio(0);

#define UTILE(tv, S, R, HASW, WV)                                       \
  {                                                                     \
    UMFMA(0);                                                           \
    LGKM0();                                                            \
    BARRIER();                                                          \
    if (S) { USG_A((tv) + 2, UABUF((tv) & 1));                          \
             USG_B(0, (tv) + 2, UBBUF((tv) & 1));                       \
             USG_B(1, (tv) + 2, UBBUF((tv) & 1)); }                     \
    UMFMA(1);                                                           \
    if (HASW) { WAITV(WV); }                                            \
    BARRIER();                                                          \
    if (R) { UREAD_A(UABUF(((tv) + 1) & 1)); UREAD_B(UBBUF(((tv) + 1) & 1)); } \
  }

__global__ __launch_bounds__(512, 1) void kgemm3(const unsigned char* __restrict__ reps8,
                                                 float* __restrict__ partial) {
  extern __shared__ char smem[];
  const int t = threadIdx.x;
  const int l = t & 63, w = t >> 6;
  const int wr = w >> 2, wc = w & 3;          // 2 x 4 wave grid
  const int q2 = (l >> 4) & 3;
  const int r7 = l & 7;
  const int off0 = ((2 * q2) ^ r7) << 4;
  const int off1 = ((2 * q2 + 1) ^ r7) << 4;

  if (blockIdx.x < 128) {
    // ================= tail path: 64x128 eighth-tiles of tiles (0,16..31) =============
    const int b = (int)blockIdx.x;              // 0..127
    const int s = b >> 3, sub = b & 7;
    const int qr = sub >> 1;                    // 64-row chunk of rows 0..255
    const int qc = sub & 1;                     // 128-col half of the 256-col tile
    const int cbt = 16 + s;

    f32x4 uacc[2][2];
    const f32x4 zero4t = {0.f, 0.f, 0.f, 0.f};
#pragma unroll
    for (int m = 0; m < 2; m++)
#pragma unroll
      for (int n = 0; n < 2; n++) uacc[m][n] = zero4t;

    const size_t uarow0 = (size_t)qr * 64;
    const size_t ubrow0 = (size_t)cbt * 256 + (size_t)qc * 128;
    const int uarow = wr * 32 + (l & 15);
    const int ubrow = wc * 32 + (l & 15);

    USG_A(0, 0); USG_B(0, 0, 16384); USG_B(1, 0, 16384);
    USG_A(1, 8192); USG_B(0, 1, 32768); USG_B(1, 1, 32768);
    WAITV(3);
    BARRIER();

    i32x8 ua[2], ub[2];
    UREAD_A(0); UREAD_B(16384);

    UTILE(0, 1, 1, 1, 3)
    UTILE(1, 1, 1, 1, 3)
    UTILE(2, 1, 1, 1, 3)
    UTILE(3, 1, 1, 1, 3)
    UTILE(4, 1, 1, 1, 3)
    UTILE(5, 1, 1, 1, 3)
    UTILE(6, 0, 1, 1, 0)
    UTILE(7, 0, 0, 0, 0)

    float rsum[2][4];
    float csum[2];
#pragma unroll
    for (int m = 0; m < 2; m++)
#pragma unroll
      for (int j = 0; j < 4; j++) rsum[m][j] = 0.f;
    csum[0] = 0.f; csum[1] = 0.f;

#pragma unroll
    for (int m = 0; m < 2; m++)
#pragma unroll
      for (int n = 0; n < 2; n++)
#pragma unroll
        for (int j = 0; j < 4; j++) {
          const float e = exp2f(uacc[m][n][j] * EXPSCALE);
          rsum[m][j] += e;
          csum[n] += e;
        }
#pragma unroll
    for (int m = 0; m < 2; m++)
#pragma unroll
      for (int j = 0; j < 4; j++) {
        float v = rsum[m][j];
        v += __shfl_xor(v, 1); v += __shfl_xor(v, 2);
        v += __shfl_xor(v, 4); v += __shfl_xor(v, 8);
        rsum[m][j] = v;
      }
#pragma unroll
    for (int n = 0; n < 2; n++) {
      float v = csum[n];
      v += __shfl_xor(v, 16); v += __shfl_xor(v, 32);
      csum[n] = v;
    }

    const int col16 = l & 15, rgp = (l >> 4) & 3;
    float* rS = (float*)smem;            // [4 wc][64 rows]
    float* cS = ((float*)smem) + 256;    // [2 wr][128 cols]
    if (col16 == 0) {
#pragma unroll
      for (int m = 0; m < 2; m++)
#pragma unroll
        for (int j = 0; j < 4; j++)
          rS[wc * 64 + wr * 32 + m * 16 + rgp * 4 + j] = rsum[m][j];
    }
    if (rgp == 0) {
#pragma unroll
      for (int n = 0; n < 2; n++)
        cS[wr * 128 + wc * 32 + n * 16 + col16] = csum[n];
    }
    __syncthreads();
    if (t < 64) {
      const float rs = rS[t] + rS[64 + t] + rS[128 + t] + rS[192 + t];
      partial[(size_t)(cbt * 2 + qc) * N2 + qr * 64 + t] = rs;
    }
    if (t < 128) {
      const float cs = cS[t] + cS[128 + t];
      partial[(size_t)(64 + qr) * N2 + cbt * 256 + qc * 128 + t] = cs;
    }
    return;
  }

  // ================= main path: 256x256 MX-fp8 tiles =================================
  int bid = (int)blockIdx.x - 128;
  bid = (bid & 7) * 64 + (bid >> 3);   // XCD swizzle (512 = 8*64, bijective)
  int rb, cb;
  if (bid < 16) {
    rb = 0; cb = bid;
  } else {
    int rem = bid - 16;
    rb = 1;
    while (rem >= NTB - rb) { rem -= NTB - rb; rb++; }
    cb = rb + rem;
  }

  f32x4 acc[8][4];
  const f32x4 zero4 = {0.f, 0.f, 0.f, 0.f};
#pragma unroll
  for (int m = 0; m < 8; m++)
#pragma unroll
    for (int n = 0; n < 4; n++) acc[m][n] = zero4;

  const size_t arow0 = (size_t)rb * 256;
  const size_t brow0 = (size_t)cb * 256;

  const int arow = wr * 128 + (l & 15);
  const int brow = wc * 64 + (l & 15);
  const int aaddr0 = arow * 128 + off0;
  const int aaddr1 = arow * 128 + off1;
  const int baddr0 = brow * 128 + off0;
  const int baddr1 = brow * 128 + off1;

  // ---- prologue: B(0), A(0), B(1), A(1); retire B(0)+A(0); preload tile-0 ph1 ops ----
  SG_B(0, 0, smem + 32768); SG_B(1, 0, smem + 32768);
  SG_B(2, 0, smem + 32768); SG_B(3, 0, smem + 32768);
  SG_A(0, 0, smem); SG_A(1, 0, smem); SG_A(2, 0, smem); SG_A(3, 0, smem);
  SG_B(0, 1, smem + 49152); SG_B(1, 1, smem + 49152);
  SG_B(2, 1, smem + 49152); SG_B(3, 1, smem + 49152);
  SG_A(0, 1, smem + 16384); SG_A(1, 1, smem + 16384);
  SG_A(2, 1, smem + 16384); SG_A(3, 1, smem + 16384);
  WAITV(8);
  BARRIER();

  i32x8 afp[2], bfp[4];
  READ_A2(0, 0);
  READ_B2(32768, 0);
  READ_B2(32768, 1);

  DO_TILE(0, 1, 1, 1, 1, 4)
  DO_TILE(1, 1, 1, 1, 1, 4)
  DO_TILE(2, 1, 1, 1, 1, 4)
  DO_TILE(3, 1, 1, 1, 1, 4)
  DO_TILE(4, 1, 1, 1, 1, 4)
  DO_TILE(5, 1, 1, 1, 1, 4)
  DO_TILE(6, 0, 0, 1, 1, 0)
  DO_TILE(7, 0, 0, 0, 0, 0)

  // -------- epilogue: exp + diagonal mask + row/col partial sums --------
  float rsum[8][4];
  float csum[4];
#pragma unroll
  for (int m = 0; m < 8; m++)
#pragma unroll
    for (int j = 0; j < 4; j++) rsum[m][j] = 0.f;
#pragma unroll
  for (int n = 0; n < 4; n++) csum[n] = 0.f;

  const int col16 = l & 15, rgp = (l >> 4) & 3;
  const bool diag = (rb == cb);
  const int growbase = wr * 128 + rgp * 4;
  const int gcolbase = wc * 64 + col16;
#pragma unroll
  for (int m = 0; m < 8; m++) {
#pragma unroll
    for (int n = 0; n < 4; n++) {
#pragma unroll
      for (int j = 0; j < 4; j++) {
        const float e = (diag && (growbase + m * 16 + j) == (gcolbase + n * 16))
                            ? 0.f
                            : exp2f(acc[m][n][j] * EXPSCALE);
        rsum[m][j] += e;
        csum[n] += e;
      }
    }
  }
#pragma unroll
  for (int m = 0; m < 8; m++)
#pragma unroll
    for (int j = 0; j < 4; j++) {
      float v = rsum[m][j];
      v += __shfl_xor(v, 1); v += __shfl_xor(v, 2);
      v += __shfl_xor(v, 4); v += __shfl_xor(v, 8);
      rsum[m][j] = v;
    }
#pragma unroll
  for (int n = 0; n < 4; n++) {
    float v = csum[n];
    v += __shfl_xor(v, 16); v += __shfl_xor(v, 32);
    csum[n] = v;
  }

  __syncthreads();   // all waves done with LDS tiles before reuse as reduction scratch
  float* rS = (float*)smem;            // [4 wc][256 rows]
  float* cS = ((float*)smem) + 1024;   // [2 wr][256 cols]
  if (col16 == 0) {
#pragma unroll
    for (int m = 0; m < 8; m++)
#pragma unroll
      for (int j = 0; j < 4; j++)
        rS[wc * 256 + wr * 128 + m * 16 + rgp * 4 + j] = rsum[m][j];
  }
  if (rgp == 0) {
#pragma unroll
    for (int n = 0; n < 4; n++)
      cS[wr * 256 + wc * 64 + n * 16 + col16] = csum[n];
  }
  __syncthreads();
  // partial layout: [68 col-blocks of 128][8192 rows]
  if (t < 256) {
    const float rs_lo = rS[t] + rS[256 + t];
    const float rs_hi = rS[512 + t] + rS[768 + t];
    partial[(size_t)(cb * 2) * N2 + rb * 256 + t] = rs_lo;
    partial[(size_t)(cb * 2 + 1) * N2 + rb * 256 + t] = rs_hi;
    if (!diag) {
      partial[(size_t)(rb * 2) * N2 + cb * 256 + t] = cS[t];
      partial[(size_t)(rb * 2 + 1) * N2 + cb * 256 + t] = cS[256 + t];
    }
  }
}

// ---------------- Kernel C: per-row denom + fused final scalar (last-block) ---------------
__device__ inline float blockReduce(float v, float* sred) {
#pragma unroll
  for (int o = 32; o > 0; o >>= 1) v += __shfl_xor(v, o);
  const int lane = threadIdx.x & 63, wid = threadIdx.x >> 6;
  if (lane == 0) sred[wid] = v;
  __syncthreads();
  v = sred[0] + sred[1] + sred[2] + sred[3];
  __syncthreads();
  return v;
}

__global__ __launch_bounds__(256) void kred1(const float* __restrict__ partial,
                                             const float* __restrict__ pos,
                                             float* __restrict__ bsum,
                                             int* __restrict__ cnt,
                                             float* __restrict__ out) {
  const int r = blockIdx.x * 256 + threadIdx.x;
  float d = 0.f;
#pragma unroll 8
  for (int cbx = 0; cbx < 64; ++cbx) d += partial[(size_t)cbx * N2 + r];
  if (blockIdx.x >= 16) {   // rows >= 4096: add tail colsum slots 64..67
#pragma unroll
    for (int cbx = 64; cbx < 68; ++cbx) d += partial[(size_t)cbx * N2 + r];
  }
  float v = logf(d);
  __shared__ float sred[4];
  __shared__ int lastFlag;
  v = blockReduce(v, sred);
  if (threadIdx.x == 0) {
    bsum[blockIdx.x] = v;
    __threadfence();
    lastFlag = (atomicAdd(cnt, 1) == 31);
  }
  __syncthreads();
  if (!lastFlag) return;
  __threadfence();
  float s = (threadIdx.x < 32) ? ((volatile float*)bsum)[threadIdx.x] : 0.f;
  float p = 0.f;
  for (int k = threadIdx.x; k < BSZ; k += 256) p += pos[k];
  s = blockReduce(s, sred);
  p = blockReduce(p, sred);
  if (threadIdx.x == 0) out[0] = (s - 2.0f * p / TEMPV) / (float)N2;
}

extern "C" void kernel_launch(void* const* d_in, const int* in_sizes, int n_in,
                              void* d_out, int out_size, void* d_ws, size_t ws_size,
                              hipStream_t stream) {
  const float* ei = (const float*)d_in[0];
  const float* ej = (const float*)d_in[1];
  char* ws = (char*)d_ws;
  unsigned char* reps8 = (unsigned char*)ws;                           // 8 MB fp8 [8192][1024]
  float* partial = (float*)(ws + (size_t)8 * 1024 * 1024);             // 2.13 MB [68][8192]
  float* pos = (float*)(ws + (size_t)8 * 1024 * 1024 + 2304 * 1024);   // 16 KB [4096]
  float* bsum = (float*)(ws + (size_t)8 * 1024 * 1024 + 2304 * 1024 + 16384); // 128 B
  int* cnt = (int*)(ws + (size_t)8 * 1024 * 1024 + 2304 * 1024 + 16384 + 256);

  (void)hipFuncSetAttribute((const void*)kgemm3,
                            hipFuncAttributeMaxDynamicSharedMemorySize, 131072);

  knorm<<<BSZ, 256, 0, stream>>>(ei, ej, reps8, pos, cnt);
  kgemm3<<<640, 512, 131072, stream>>>(reps8, partial);
  kred1<<<32, 256, 0, stream>>>(partial, pos, bsum, cnt, (float*)d_out);
}

// Round 19
// 68.366 us; speedup vs baseline: 1.0158x; 1.0158x over previous
//
#include <hip/hip_runtime.h>

#define BSZ 4096
#define D 1024
#define N2 8192
#define TEMPV 0.5f
// exp(x/T) = exp2(x * log2(e)/T)
#define EXPSCALE 2.8853900817779268f
#define NTB 32      // 8192 / 256 tiles per dim

typedef __attribute__((ext_vector_type(4))) float f32x4;
typedef __attribute__((ext_vector_type(4))) int i32x4;
typedef __attribute__((ext_vector_type(8))) int i32x8;

// bit-exact float -> OCP e4m3fn, RNE (inputs |x|<=1 here; clamp kept for safety)
__device__ inline unsigned int f2e4m3(float x) {
  unsigned int u = __float_as_uint(x);
  const unsigned int s = (u >> 24) & 0x80u;
  u &= 0x7fffffffu;
  const float a = __uint_as_float(u);
  if (a >= 448.0f) return s | 0x7Eu;
  if (a < 0.015625f) {                       // < 2^-6: subnormal
    const int m = (int)rintf(a * 512.0f);    // RNE; 8 -> 0x08 == 2^-6 exactly
    return s | (unsigned int)m;
  }
  u += 0x7FFFFu + ((u >> 20) & 1u);          // RNE to 3 mantissa bits
  const unsigned int e = u >> 23;            // biased f32 exp (>=121)
  const unsigned int m3 = (u >> 20) & 7u;
  return s | (((e - 120u) << 3) | m3);       // e4m3 bias 7
}

__device__ inline void gload16(const void* g, void* l) {
  __builtin_amdgcn_global_load_lds(
      (const __attribute__((address_space(1))) void*)g,
      (__attribute__((address_space(3))) void*)l, 16, 0, 0);
}

// ---------------- Kernel A: L2-normalize rows, emit fp8 reps + pos dot ------------------
__global__ __launch_bounds__(256) void knorm(const float* __restrict__ ei,
                                             const float* __restrict__ ej,
                                             unsigned char* __restrict__ reps8,
                                             float* __restrict__ pos,
                                             int* __restrict__ cnt) {
  const int r = blockIdx.x;
  const int t = threadIdx.x;
  if (r == 0 && t == 0) *cnt = 0;   // reset done-counter for fused kred (every call)
  const float4 vi = ((const float4*)(ei + (size_t)r * D))[t];
  const float4 vj = ((const float4*)(ej + (size_t)r * D))[t];
  float ssi = vi.x * vi.x + vi.y * vi.y + vi.z * vi.z + vi.w * vi.w;
  float ssj = vj.x * vj.x + vj.y * vj.y + vj.z * vj.z + vj.w * vj.w;
  float sij = vi.x * vj.x + vi.y * vj.y + vi.z * vj.z + vi.w * vj.w;
#pragma unroll
  for (int o = 32; o > 0; o >>= 1) {
    ssi += __shfl_xor(ssi, o);
    ssj += __shfl_xor(ssj, o);
    sij += __shfl_xor(sij, o);
  }
  __shared__ float red[12];
  const int lane = t & 63, wid = t >> 6;
  if (lane == 0) { red[wid * 3] = ssi; red[wid * 3 + 1] = ssj; red[wid * 3 + 2] = sij; }
  __syncthreads();
  ssi = red[0] + red[3] + red[6] + red[9];
  ssj = red[1] + red[4] + red[7] + red[10];
  sij = red[2] + red[5] + red[8] + red[11];
  const float inv_i = rsqrtf(fmaxf(ssi, 1e-24f));
  const float inv_j = rsqrtf(fmaxf(ssj, 1e-24f));
  const float xi0 = vi.x * inv_i, xi1 = vi.y * inv_i, xi2 = vi.z * inv_i, xi3 = vi.w * inv_i;
  const float xj0 = vj.x * inv_j, xj1 = vj.y * inv_j, xj2 = vj.z * inv_j, xj3 = vj.w * inv_j;
  const unsigned int pi = f2e4m3(xi0) | (f2e4m3(xi1) << 8) | (f2e4m3(xi2) << 16) | (f2e4m3(xi3) << 24);
  const unsigned int pj = f2e4m3(xj0) | (f2e4m3(xj1) << 8) | (f2e4m3(xj2) << 16) | (f2e4m3(xj3) << 24);
  *(unsigned int*)(reps8 + (size_t)r * 1024 + t * 4) = pi;
  *(unsigned int*)(reps8 + (size_t)(BSZ + r) * 1024 + t * 4) = pj;
  if (t == 0) pos[r] = sij * inv_i * inv_j;
}

// ======================= shared asm helpers =======================
#define BARRIER() do { __builtin_amdgcn_s_barrier(); asm volatile("" ::: "memory"); } while (0)
#define STR2(x) #x
#define WAITV(n) asm volatile("s_waitcnt vmcnt(" STR2(n) ")" ::: "memory")
#define LGKM0() asm volatile("s_waitcnt lgkmcnt(0)" ::: "memory")

// ---------------- Kernel B (merged): tails FIRST (0..127), mains (128..639) -------------
// R15 engine verbatim (best measured): 256x256 MX-fp8 tile (unit scales), BK=128,
// 8 waves (2Mx4N), wave tile 128x64, LDS 128 KiB (A dbuf @0/@16384, B dbuf @32768/
// @49152), fully unrolled 8 K-tiles, 4 barriers/tile, WAITV(4) ledger.
#define SG_A(ii, ktv, dst) gload16(reps8 + (size_t)(arow0 + (ii) * 64 + (t >> 3)) * 1024 + \
                                       (ktv) * 128 + (((t & 7) ^ ((t >> 3) & 7)) << 4),    \
                                   (dst) + (size_t)(ii) * 8192 + (size_t)t * 16)
#define SG_B(ii, ktv, dst) gload16(reps8 + (size_t)(brow0 + (ii) * 64 + (t >> 3)) * 1024 + \
                                       (ktv) * 128 + (((t & 7) ^ ((t >> 3) & 7)) << 4),    \
                                   (dst) + (size_t)(ii) * 8192 + (size_t)t * 16)

#define ABUF(c) ((c) ? 16384 : 0)
#define BBUF(c) ((c) ? 49152 : 32768)

#define READ_A2(bufoff, p) do {                                                       \
    i32x4 a0l = *(const i32x4*)(smem + (bufoff) + ((p) * 2) * 2048 + aaddr0);         \
    i32x4 a0h = *(const i32x4*)(smem + (bufoff) + ((p) * 2) * 2048 + aaddr1);         \
    i32x4 a1l = *(const i32x4*)(smem + (bufoff) + ((p) * 2 + 1) * 2048 + aaddr0);     \
    i32x4 a1h = *(const i32x4*)(smem + (bufoff) + ((p) * 2 + 1) * 2048 + aaddr1);     \
    afp[0] = __builtin_shufflevector(a0l, a0h, 0, 1, 2, 3, 4, 5, 6, 7);               \
    afp[1] = __builtin_shufflevector(a1l, a1h, 0, 1, 2, 3, 4, 5, 6, 7);               \
  } while (0)

#define READ_B2(bufoff, n) do {                                                       \
    i32x4 bl = *(const i32x4*)(smem + (bufoff) + (n) * 2048 + baddr0);                \
    i32x4 bh = *(const i32x4*)(smem + (bufoff) + (n) * 2048 + baddr1);                \
    bfp[n] = __builtin_shufflevector(bl, bh, 0, 1, 2, 3, 4, 5, 6, 7);                 \
  } while (0)

#define MFMA_P(p)                                                       \
  __builtin_amdgcn_s_setprio(1);                                        \
  _Pragma("unroll") for (int nh = 0; nh < 2; nh++)                      \
  _Pragma("unroll") for (int m2 = 0; m2 < 2; m2++)                      \
  _Pragma("unroll") for (int nn = 0; nn < 2; nn++) {                    \
    const int n_ = nh * 2 + nn;                                         \
    acc[2 * (p) + m2][n_] = __builtin_amdgcn_mfma_scale_f32_16x16x128_f8f6f4( \
        afp[m2], bfp[n_], acc[2 * (p) + m2][n_],                        \
        0, 0, 0, 0x7F7F7F7F, 0, 0x7F7F7F7F);                            \
  }                                                                     \
  __builtin_amdgcn_s_setprio(0);

#define DO_TILE(ktv, SA, SB, RDN, HASW, WV)                             \
  {                                                                     \
    READ_B2(BBUF((ktv) & 1), 2); READ_B2(BBUF((ktv) & 1), 3);           \
    MFMA_P(0);                                                          \
    READ_A2(ABUF((ktv) & 1), 1);                                        \
    if (SA) { SG_A(0, (ktv) + 1, smem + ABUF(((ktv) + 1) & 1));         \
              SG_A(1, (ktv) + 1, smem + ABUF(((ktv) + 1) & 1));         \
              SG_A(2, (ktv) + 1, smem + ABUF(((ktv) + 1) & 1));         \
              SG_A(3, (ktv) + 1, smem + ABUF(((ktv) + 1) & 1)); }       \
    BARRIER();                                                          \
    MFMA_P(1);                                                          \
    READ_A2(ABUF((ktv) & 1), 2);                                        \
    BARRIER();                                                          \
    MFMA_P(2);                                                          \
    READ_A2(ABUF((ktv) & 1), 3);                                        \
    if (SB) { SG_B(0, (ktv) + 2, smem + BBUF((ktv) & 1));               \
              SG_B(1, (ktv) + 2, smem + BBUF((ktv) & 1));               \
              SG_B(2, (ktv) + 2, smem + BBUF((ktv) & 1));               \
              SG_B(3, (ktv) + 2, smem + BBUF((ktv) & 1)); }             \
    if (HASW) { WAITV(WV); }                                            \
    BARRIER();                                                          \
    MFMA_P(3);                                                          \
    if (RDN) { READ_A2(ABUF(((ktv) + 1) & 1), 0);                       \
               READ_B2(BBUF(((ktv) + 1) & 1), 0);                       \
               READ_B2(BBUF(((ktv) + 1) & 1), 1); }                     \
    BARRIER();                                                          \
  }

// -------- tail-path macros (MX-fp8, 64x128 tile, BK=128) --------
#define UABUF(c) ((c) ? 8192 : 0)
#define UBBUF(c) ((c) ? 32768 : 16384)

#define USG_A(ktv, dstoff) gload16(reps8 + (size_t)(uarow0 + (t >> 3)) * 1024 + \
                                       (ktv) * 128 + (((t & 7) ^ ((t >> 3) & 7)) << 4), \
                                   smem + (dstoff) + (size_t)t * 16)
#define USG_B(ii, ktv, dstoff) gload16(reps8 + (size_t)(ubrow0 + (ii) * 64 + (t >> 3)) * 1024 + \
                                       (ktv) * 128 + (((t & 7) ^ ((t >> 3) & 7)) << 4), \
                                   smem + (dstoff) + (size_t)(ii) * 8192 + (size_t)t * 16)

#define UREAD_A(bufoff) do {                                                          \
    i32x4 a0l = *(const i32x4*)(smem + (bufoff) + uarow * 128 + off0);                \
    i32x4 a0h = *(const i32x4*)(smem + (bufoff) + uarow * 128 + off1);                \
    i32x4 a1l = *(const i32x4*)(smem + (bufoff) + (uarow + 16) * 128 + off0);         \
    i32x4 a1h = *(const i32x4*)(smem + (bufoff) + (uarow + 16) * 128 + off1);         \
    ua[0] = __builtin_shufflevector(a0l, a0h, 0, 1, 2, 3, 4, 5, 6, 7);                \
    ua[1] = __builtin_shufflevector(a1l, a1h, 0, 1, 2, 3, 4, 5, 6, 7);                \
  } while (0)

#define UREAD_B(bufoff) do {                                                          \
    i32x4 b0l = *(const i32x4*)(smem + (bufoff) + ubrow * 128 + off0);                \
    i32x4 b0h = *(const i32x4*)(smem + (bufoff) + ubrow * 128 + off1);                \
    i32x4 b1l = *(const i32x4*)(smem + (bufoff) + (ubrow + 16) * 128 + off0);         \
    i32x4 b1h = *(const i32x4*)(smem + (bufoff) + (ubrow + 16) * 128 + off1);         \
    ub[0] = __builtin_shufflevector(b0l, b0h, 0, 1, 2, 3, 4, 5, 6, 7);                \
    ub[1] = __builtin_shufflevector(b1l, b1h, 0, 1, 2, 3, 4, 5, 6, 7);                \
  } while (0)

#define UMFMA(n)                                                        \
  __builtin_amdgcn_s_setprio(1);                                        \
  _Pragma("unroll") for (int m2 = 0; m2 < 2; m2++)                      \
    uacc[m2][n] = __builtin_amdgcn_mfma_scale_f32_16x16x128_f8f6f4(     \
        ua[m2], ub[n], uacc[m2][n], 0, 0, 0, 0x7F7F7F7F, 0, 0x7F7F7F7F);\
  __builtin_amdgcn_s_setprio(0);

#define UTILE(tv, S, R, HASW, WV)                                       \
  {                                                                     \
    UMFMA(0);                                                           \
    LGKM0();                                                            \
    BARRIER();                                                          \
    if (S) { USG_A((tv) + 2, UABUF((tv) & 1));                          \
             USG_B(0, (tv) + 2, UBBUF((tv) & 1));                       \
             USG_B(1, (tv) + 2, UBBUF((tv) & 1)); }                     \
    UMFMA(1);                                                           \
    if (HASW) { WAITV(WV); }                                            \
    BARRIER();                                                          \
    if (R) { UREAD_A(UABUF(((tv) + 1) & 1)); UREAD_B(UBBUF(((tv) + 1) & 1)); } \
  }

__global__ __launch_bounds__(512, 1) void kgemm3(const unsigned char* __restrict__ reps8,
                                                 float* __restrict__ partial) {
  extern __shared__ char smem[];
  const int t = threadIdx.x;
  const int l = t & 63, w = t >> 6;
  const int wr = w >> 2, wc = w & 3;          // 2 x 4 wave grid
  const int q2 = (l >> 4) & 3;
  const int r7 = l & 7;
  const int off0 = ((2 * q2) ^ r7) << 4;
  const int off1 = ((2 * q2 + 1) ^ r7) << 4;

  if (blockIdx.x < 128) {
    // ================= tail path: 64x128 eighth-tiles of tiles (0,16..31) =============
    const int b = (int)blockIdx.x;              // 0..127
    const int s = b >> 3, sub = b & 7;
    const int qr = sub >> 1;                    // 64-row chunk of rows 0..255
    const int qc = sub & 1;                     // 128-col half of the 256-col tile
    const int cbt = 16 + s;

    f32x4 uacc[2][2];
    const f32x4 zero4t = {0.f, 0.f, 0.f, 0.f};
#pragma unroll
    for (int m = 0; m < 2; m++)
#pragma unroll
      for (int n = 0; n < 2; n++) uacc[m][n] = zero4t;

    const size_t uarow0 = (size_t)qr * 64;
    const size_t ubrow0 = (size_t)cbt * 256 + (size_t)qc * 128;
    const int uarow = wr * 32 + (l & 15);
    const int ubrow = wc * 32 + (l & 15);

    USG_A(0, 0); USG_B(0, 0, 16384); USG_B(1, 0, 16384);
    USG_A(1, 8192); USG_B(0, 1, 32768); USG_B(1, 1, 32768);
    WAITV(3);
    BARRIER();

    i32x8 ua[2], ub[2];
    UREAD_A(0); UREAD_B(16384);

    UTILE(0, 1, 1, 1, 3)
    UTILE(1, 1, 1, 1, 3)
    UTILE(2, 1, 1, 1, 3)
    UTILE(3, 1, 1, 1, 3)
    UTILE(4, 1, 1, 1, 3)
    UTILE(5, 1, 1, 1, 3)
    UTILE(6, 0, 1, 1, 0)
    UTILE(7, 0, 0, 0, 0)

    float rsum[2][4];
    float csum[2];
#pragma unroll
    for (int m = 0; m < 2; m++)
#pragma unroll
      for (int j = 0; j < 4; j++) rsum[m][j] = 0.f;
    csum[0] = 0.f; csum[1] = 0.f;

#pragma unroll
    for (int m = 0; m < 2; m++)
#pragma unroll
      for (int n = 0; n < 2; n++)
#pragma unroll
        for (int j = 0; j < 4; j++) {
          const float e = exp2f(uacc[m][n][j] * EXPSCALE);
          rsum[m][j] += e;
          csum[n] += e;
        }
#pragma unroll
    for (int m = 0; m < 2; m++)
#pragma unroll
      for (int j = 0; j < 4; j++) {
        float v = rsum[m][j];
        v += __shfl_xor(v, 1); v += __shfl_xor(v, 2);
        v += __shfl_xor(v, 4); v += __shfl_xor(v, 8);
        rsum[m][j] = v;
      }
#pragma unroll
    for (int n = 0; n < 2; n++) {
      float v = csum[n];
      v += __shfl_xor(v, 16); v += __shfl_xor(v, 32);
      csum[n] = v;
    }

    const int col16 = l & 15, rgp = (l >> 4) & 3;
    float* rS = (float*)smem;            // [4 wc][64 rows]
    float* cS = ((float*)smem) + 256;    // [2 wr][128 cols]
    if (col16 == 0) {
#pragma unroll
      for (int m = 0; m < 2; m++)
#pragma unroll
        for (int j = 0; j < 4; j++)
          rS[wc * 64 + wr * 32 + m * 16 + rgp * 4 + j] = rsum[m][j];
    }
    if (rgp == 0) {
#pragma unroll
      for (int n = 0; n < 2; n++)
        cS[wr * 128 + wc * 32 + n * 16 + col16] = csum[n];
    }
    __syncthreads();
    if (t < 64) {
      const float rs = rS[t] + rS[64 + t] + rS[128 + t] + rS[192 + t];
      partial[(size_t)(cbt * 2 + qc) * N2 + qr * 64 + t] = rs;
    }
    if (t < 128) {
      const float cs = cS[t] + cS[128 + t];
      partial[(size_t)(64 + qr) * N2 + cbt * 256 + qc * 128 + t] = cs;
    }
    return;
  }

  // ================= main path: 256x256 MX-fp8 tiles =================================
  int bid = (int)blockIdx.x - 128;
  bid = (bid & 7) * 64 + (bid >> 3);   // XCD swizzle (512 = 8*64, bijective)
  int rb, cb;
  if (bid < 16) {
    rb = 0; cb = bid;
  } else {
    int rem = bid - 16;
    rb = 1;
    while (rem >= NTB - rb) { rem -= NTB - rb; rb++; }
    cb = rb + rem;
  }

  f32x4 acc[8][4];
  const f32x4 zero4 = {0.f, 0.f, 0.f, 0.f};
#pragma unroll
  for (int m = 0; m < 8; m++)
#pragma unroll
    for (int n = 0; n < 4; n++) acc[m][n] = zero4;

  const size_t arow0 = (size_t)rb * 256;
  const size_t brow0 = (size_t)cb * 256;

  const int arow = wr * 128 + (l & 15);
  const int brow = wc * 64 + (l & 15);
  const int aaddr0 = arow * 128 + off0;
  const int aaddr1 = arow * 128 + off1;
  const int baddr0 = brow * 128 + off0;
  const int baddr1 = brow * 128 + off1;

  // ---- prologue: B(0), A(0), B(1); retire B(0)+A(0); preload tile-0 ph1 ops ----
  SG_B(0, 0, smem + 32768); SG_B(1, 0, smem + 32768);
  SG_B(2, 0, smem + 32768); SG_B(3, 0, smem + 32768);
  SG_A(0, 0, smem); SG_A(1, 0, smem); SG_A(2, 0, smem); SG_A(3, 0, smem);
  SG_B(0, 1, smem + 49152); SG_B(1, 1, smem + 49152);
  SG_B(2, 1, smem + 49152); SG_B(3, 1, smem + 49152);
  WAITV(4);
  BARRIER();

  i32x8 afp[2], bfp[4];
  READ_A2(0, 0);
  READ_B2(32768, 0);
  READ_B2(32768, 1);

  DO_TILE(0, 1, 1, 1, 1, 4)
  DO_TILE(1, 1, 1, 1, 1, 4)
  DO_TILE(2, 1, 1, 1, 1, 4)
  DO_TILE(3, 1, 1, 1, 1, 4)
  DO_TILE(4, 1, 1, 1, 1, 4)
  DO_TILE(5, 1, 1, 1, 1, 4)
  DO_TILE(6, 1, 0, 1, 1, 0)
  DO_TILE(7, 0, 0, 0, 0, 0)

  // -------- epilogue: exp + diagonal mask + row/col partial sums --------
  float rsum[8][4];
  float csum[4];
#pragma unroll
  for (int m = 0; m < 8; m++)
#pragma unroll
    for (int j = 0; j < 4; j++) rsum[m][j] = 0.f;
#pragma unroll
  for (int n = 0; n < 4; n++) csum[n] = 0.f;

  const int col16 = l & 15, rgp = (l >> 4) & 3;
  const bool diag = (rb == cb);
  const int growbase = wr * 128 + rgp * 4;
  const int gcolbase = wc * 64 + col16;
#pragma unroll
  for (int m = 0; m < 8; m++) {
#pragma unroll
    for (int n = 0; n < 4; n++) {
#pragma unroll
      for (int j = 0; j < 4; j++) {
        const float e = (diag && (growbase + m * 16 + j) == (gcolbase + n * 16))
                            ? 0.f
                            : exp2f(acc[m][n][j] * EXPSCALE);
        rsum[m][j] += e;
        csum[n] += e;
      }
    }
  }
#pragma unroll
  for (int m = 0; m < 8; m++)
#pragma unroll
    for (int j = 0; j < 4; j++) {
      float v = rsum[m][j];
      v += __shfl_xor(v, 1); v += __shfl_xor(v, 2);
      v += __shfl_xor(v, 4); v += __shfl_xor(v, 8);
      rsum[m][j] = v;
    }
#pragma unroll
  for (int n = 0; n < 4; n++) {
    float v = csum[n];
    v += __shfl_xor(v, 16); v += __shfl_xor(v, 32);
    csum[n] = v;
  }

  __syncthreads();   // all waves done with LDS tiles before reuse as reduction scratch
  float* rS = (float*)smem;            // [4 wc][256 rows]
  float* cS = ((float*)smem) + 1024;   // [2 wr][256 cols]
  if (col16 == 0) {
#pragma unroll
    for (int m = 0; m < 8; m++)
#pragma unroll
      for (int j = 0; j < 4; j++)
        rS[wc * 256 + wr * 128 + m * 16 + rgp * 4 + j] = rsum[m][j];
  }
  if (rgp == 0) {
#pragma unroll
    for (int n = 0; n < 4; n++)
      cS[wr * 256 + wc * 64 + n * 16 + col16] = csum[n];
  }
  __syncthreads();
  // partial layout: [68 col-blocks of 128][8192 rows]
  if (t < 256) {
    const float rs_lo = rS[t] + rS[256 + t];
    const float rs_hi = rS[512 + t] + rS[768 + t];
    partial[(size_t)(cb * 2) * N2 + rb * 256 + t] = rs_lo;
    partial[(size_t)(cb * 2 + 1) * N2 + rb * 256 + t] = rs_hi;
    if (!diag) {
      partial[(size_t)(rb * 2) * N2 + cb * 256 + t] = cS[t];
      partial[(size_t)(rb * 2 + 1) * N2 + cb * 256 + t] = cS[256 + t];
    }
  }
}

// ---------------- Kernel C: per-row denom + fused final scalar (last-block) ---------------
__device__ inline float blockReduce(float v, float* sred) {
#pragma unroll
  for (int o = 32; o > 0; o >>= 1) v += __shfl_xor(v, o);
  const int lane = threadIdx.x & 63, wid = threadIdx.x >> 6;
  if (lane == 0) sred[wid] = v;
  __syncthreads();
  v = sred[0] + sred[1] + sred[2] + sred[3];
  __syncthreads();
  return v;
}

__global__ __launch_bounds__(256) void kred1(const float* __restrict__ partial,
                                             const float* __restrict__ pos,
                                             float* __restrict__ bsum,
                                             int* __restrict__ cnt,
                                             float* __restrict__ out) {
  const int r = blockIdx.x * 256 + threadIdx.x;
  float d = 0.f;
#pragma unroll 8
  for (int cbx = 0; cbx < 64; ++cbx) d += partial[(size_t)cbx * N2 + r];
  if (blockIdx.x >= 16) {   // rows >= 4096: add tail colsum slots 64..67
#pragma unroll
    for (int cbx = 64; cbx < 68; ++cbx) d += partial[(size_t)cbx * N2 + r];
  }
  float v = logf(d);
  __shared__ float sred[4];
  __shared__ int lastFlag;
  v = blockReduce(v, sred);
  if (threadIdx.x == 0) {
    bsum[blockIdx.x] = v;
    __threadfence();
    lastFlag = (atomicAdd(cnt, 1) == 31);
  }
  __syncthreads();
  if (!lastFlag) return;
  __threadfence();
  float s = (threadIdx.x < 32) ? ((volatile float*)bsum)[threadIdx.x] : 0.f;
  float p = 0.f;
  for (int k = threadIdx.x; k < BSZ; k += 256) p += pos[k];
  s = blockReduce(s, sred);
  p = blockReduce(p, sred);
  if (threadIdx.x == 0) out[0] = (s - 2.0f * p / TEMPV) / (float)N2;
}

extern "C" void kernel_launch(void* const* d_in, const int* in_sizes, int n_in,
                              void* d_out, int out_size, void* d_ws, size_t ws_size,
                              hipStream_t stream) {
  const float* ei = (const float*)d_in[0];
  const float* ej = (const float*)d_in[1];
  char* ws = (char*)d_ws;
  unsigned char* reps8 = (unsigned char*)ws;                           // 8 MB fp8 [8192][1024]
  float* partial = (float*)(ws + (size_t)8 * 1024 * 1024);             // 2.13 MB [68][8192]
  float* pos = (float*)(ws + (size_t)8 * 1024 * 1024 + 2304 * 1024);   // 16 KB [4096]
  float* bsum = (float*)(ws + (size_t)8 * 1024 * 1024 + 2304 * 1024 + 16384); // 128 B
  int* cnt = (int*)(ws + (size_t)8 * 1024 * 1024 + 2304 * 1024 + 16384 + 256);

  (void)hipFuncSetAttribute((const void*)kgemm3,
                            hipFuncAttributeMaxDynamicSharedMemorySize, 131072);

  knorm<<<BSZ, 256, 0, stream>>>(ei, ej, reps8, pos, cnt);
  kgemm3<<<640, 512, 131072, stream>>>(reps8, partial);
  kred1<<<32, 256, 0, stream>>>(partial, pos, bsum, cnt, (float*)d_out);
}

// Round 20
// 61.628 us; speedup vs baseline: 1.1269x; 1.1093x over previous
//
#include <hip/hip_runtime.h>

#define BSZ 4096
#define D 1024
#define N2 8192
#define TEMPV 0.5f
// exp(x/T) = exp2(x * log2(e)/T)
#define EXPSCALE 2.8853900817779268f
#define NTB 32      // 8192 / 256 tiles per dim

typedef __attribute__((ext_vector_type(4))) float f32x4;
typedef __attribute__((ext_vector_type(4))) int i32x4;
typedef __attribute__((ext_vector_type(8))) int i32x8;

// bit-exact float -> OCP e4m3fn, RNE (inputs |x|<=1 here; clamp kept for safety)
__device__ inline unsigned int f2e4m3(float x) {
  unsigned int u = __float_as_uint(x);
  const unsigned int s = (u >> 24) & 0x80u;
  u &= 0x7fffffffu;
  const float a = __uint_as_float(u);
  if (a >= 448.0f) return s | 0x7Eu;
  if (a < 0.015625f) {                       // < 2^-6: subnormal
    const int m = (int)rintf(a * 512.0f);    // RNE; 8 -> 0x08 == 2^-6 exactly
    return s | (unsigned int)m;
  }
  u += 0x7FFFFu + ((u >> 20) & 1u);          // RNE to 3 mantissa bits
  const unsigned int e = u >> 23;            // biased f32 exp (>=121)
  const unsigned int m3 = (u >> 20) & 7u;
  return s | (((e - 120u) << 3) | m3);       // e4m3 bias 7
}

// float (pre-scaled by 32) -> fp4 e2m1 code, nearest; code==bit pattern
__device__ inline unsigned int f2e2m1(float y) {
  const float a = fabsf(y);
  unsigned int c = (unsigned int)(a > 0.25f) + (unsigned int)(a > 0.75f) +
                   (unsigned int)(a > 1.25f) + (unsigned int)(a > 1.75f) +
                   (unsigned int)(a > 2.5f) + (unsigned int)(a > 3.5f) +
                   (unsigned int)(a > 5.0f);
  return c | ((__float_as_uint(y) >> 28) & 8u);
}

__device__ inline void gload16(const void* g, void* l) {
  __builtin_amdgcn_global_load_lds(
      (const __attribute__((address_space(1))) void*)g,
      (__attribute__((address_space(3))) void*)l, 16, 0, 0);
}

// ---------------- Kernel A: L2-normalize rows, emit fp8 + fp4 reps + pos ---------------
__global__ __launch_bounds__(256) void knorm(const float* __restrict__ ei,
                                             const float* __restrict__ ej,
                                             unsigned char* __restrict__ reps8,
                                             unsigned char* __restrict__ reps4,
                                             float* __restrict__ pos,
                                             int* __restrict__ cnt) {
  const int r = blockIdx.x;
  const int t = threadIdx.x;
  if (r == 0 && t == 0) *cnt = 0;   // reset done-counter for fused kred (every call)
  const float4 vi = ((const float4*)(ei + (size_t)r * D))[t];
  const float4 vj = ((const float4*)(ej + (size_t)r * D))[t];
  float ssi = vi.x * vi.x + vi.y * vi.y + vi.z * vi.z + vi.w * vi.w;
  float ssj = vj.x * vj.x + vj.y * vj.y + vj.z * vj.z + vj.w * vj.w;
  float sij = vi.x * vj.x + vi.y * vj.y + vi.z * vj.z + vi.w * vj.w;
#pragma unroll
  for (int o = 32; o > 0; o >>= 1) {
    ssi += __shfl_xor(ssi, o);
    ssj += __shfl_xor(ssj, o);
    sij += __shfl_xor(sij, o);
  }
  __shared__ float red[12];
  const int lane = t & 63, wid = t >> 6;
  if (lane == 0) { red[wid * 3] = ssi; red[wid * 3 + 1] = ssj; red[wid * 3 + 2] = sij; }
  __syncthreads();
  ssi = red[0] + red[3] + red[6] + red[9];
  ssj = red[1] + red[4] + red[7] + red[10];
  sij = red[2] + red[5] + red[8] + red[11];
  const float inv_i = rsqrtf(fmaxf(ssi, 1e-24f));
  const float inv_j = rsqrtf(fmaxf(ssj, 1e-24f));
  const float xi0 = vi.x * inv_i, xi1 = vi.y * inv_i, xi2 = vi.z * inv_i, xi3 = vi.w * inv_i;
  const float xj0 = vj.x * inv_j, xj1 = vj.y * inv_j, xj2 = vj.z * inv_j, xj3 = vj.w * inv_j;
  const unsigned int pi = f2e4m3(xi0) | (f2e4m3(xi1) << 8) | (f2e4m3(xi2) << 16) | (f2e4m3(xi3) << 24);
  const unsigned int pj = f2e4m3(xj0) | (f2e4m3(xj1) << 8) | (f2e4m3(xj2) << 16) | (f2e4m3(xj3) << 24);
  *(unsigned int*)(reps8 + (size_t)r * 1024 + t * 4) = pi;
  *(unsigned int*)(reps8 + (size_t)(BSZ + r) * 1024 + t * 4) = pj;
  // fp4 (values pre-scaled by 32; MFMA applies 2^-5 block scales on both sides)
  const unsigned int qi = f2e2m1(xi0 * 32.f) | (f2e2m1(xi1 * 32.f) << 4) |
                          (f2e2m1(xi2 * 32.f) << 8) | (f2e2m1(xi3 * 32.f) << 12);
  const unsigned int qj = f2e2m1(xj0 * 32.f) | (f2e2m1(xj1 * 32.f) << 4) |
                          (f2e2m1(xj2 * 32.f) << 8) | (f2e2m1(xj3 * 32.f) << 12);
  *(unsigned short*)(reps4 + (size_t)r * 512 + t * 2) = (unsigned short)qi;
  *(unsigned short*)(reps4 + (size_t)(BSZ + r) * 512 + t * 2) = (unsigned short)qj;
  if (t == 0) pos[r] = sij * inv_i * inv_j;
}

// ======================= shared asm helpers =======================
#define BARRIER() do { __builtin_amdgcn_s_barrier(); asm volatile("" ::: "memory"); } while (0)
#define STR2(x) #x
#define WAITV(n) asm volatile("s_waitcnt vmcnt(" STR2(n) ")" ::: "memory")
#define LGKM0() asm volatile("s_waitcnt lgkmcnt(0)" ::: "memory")

// ---------------- Kernel B (merged): tails FIRST (0..127, fp8), mains (128..639, fp4) ---
// Main: 256x256 MX-fp4 tile, BK=128 (rows = 64B), 8 waves (2Mx4N), wave tile 128x64.
// LDS 64 KiB: A dbuf @0/@16384, B dbuf @32768/@49152. Swizzle: 16B chunk c stored at
// c ^ ((row>>1)&3); read off = (q2 ^ ((row>>1)&3))<<4 -> 2-way bank pattern (free).
// fp4 operand = one b128/lane, DUPLICATED into both halves of the 8-reg operand
// (correct regardless of which half the f8f6f4 unit reads for FMT=4).
// Ledger (R15 halved): prologue B(0)x2,A(0)x2,B(1)x2, WAITV(2); per tile SG_A x2 @ph1,
// SG_B x2 @ph3, WAITV(2) at ph3 retires A(t+1)+B(t+1); tile6 WAITV(0).
#define SG_A(ii, ktv, dst) gload16(reps4 + (size_t)(arow0 + (ii) * 128 + (t >> 2)) * 512 + \
                                       (ktv) * 64 + (((t & 3) ^ ((t >> 3) & 3)) << 4),     \
                                   (dst) + (size_t)(ii) * 8192 + (size_t)t * 16)
#define SG_B(ii, ktv, dst) gload16(reps4 + (size_t)(brow0 + (ii) * 128 + (t >> 2)) * 512 + \
                                       (ktv) * 64 + (((t & 3) ^ ((t >> 3) & 3)) << 4),     \
                                   (dst) + (size_t)(ii) * 8192 + (size_t)t * 16)

#define ABUF(c) ((c) ? 16384 : 0)
#define BBUF(c) ((c) ? 49152 : 32768)

#define READ_A2(bufoff, p) do {                                                       \
    i32x4 a0 = *(const i32x4*)(smem + (bufoff) + aaddr + ((p) * 2) * 1024);           \
    i32x4 a1 = *(const i32x4*)(smem + (bufoff) + aaddr + ((p) * 2 + 1) * 1024);       \
    afp[0] = __builtin_shufflevector(a0, a0, 0, 1, 2, 3, 0, 1, 2, 3);                 \
    afp[1] = __builtin_shufflevector(a1, a1, 0, 1, 2, 3, 0, 1, 2, 3);                 \
  } while (0)

#define READ_B2(bufoff, n) do {                                                       \
    i32x4 b0 = *(const i32x4*)(smem + (bufoff) + baddr + (n) * 1024);                 \
    bfp[n] = __builtin_shufflevector(b0, b0, 0, 1, 2, 3, 0, 1, 2, 3);                 \
  } while (0)

#define MFMA_P(p)                                                       \
  __builtin_amdgcn_s_setprio(1);                                        \
  _Pragma("unroll") for (int nh = 0; nh < 2; nh++)                      \
  _Pragma("unroll") for (int m2 = 0; m2 < 2; m2++)                      \
  _Pragma("unroll") for (int nn = 0; nn < 2; nn++) {                    \
    const int n_ = nh * 2 + nn;                                         \
    acc[2 * (p) + m2][n_] = __builtin_amdgcn_mfma_scale_f32_16x16x128_f8f6f4( \
        afp[m2], bfp[n_], acc[2 * (p) + m2][n_],                        \
        4, 4, 0, 0x7A7A7A7A, 0, 0x7A7A7A7A);                            \
  }                                                                     \
  __builtin_amdgcn_s_setprio(0);

#define DO_TILE(ktv, SA, SB, RDN, HASW, WV)                             \
  {                                                                     \
    READ_B2(BBUF((ktv) & 1), 2); READ_B2(BBUF((ktv) & 1), 3);           \
    MFMA_P(0);                                                          \
    READ_A2(ABUF((ktv) & 1), 1);                                        \
    if (SA) { SG_A(0, (ktv) + 1, smem + ABUF(((ktv) + 1) & 1));         \
              SG_A(1, (ktv) + 1, smem + ABUF(((ktv) + 1) & 1)); }       \
    BARRIER();                                                          \
    MFMA_P(1);                                                          \
    READ_A2(ABUF((ktv) & 1), 2);                                        \
    BARRIER();                                                          \
    MFMA_P(2);                                                          \
    READ_A2(ABUF((ktv) & 1), 3);                                        \
    if (SB) { SG_B(0, (ktv) + 2, smem + BBUF((ktv) & 1));               \
              SG_B(1, (ktv) + 2, smem + BBUF((ktv) & 1)); }             \
    if (HASW) { WAITV(WV); }                                            \
    BARRIER();                                                          \
    MFMA_P(3);                                                          \
    if (RDN) { READ_A2(ABUF(((ktv) + 1) & 1), 0);                       \
               READ_B2(BBUF(((ktv) + 1) & 1), 0);                       \
               READ_B2(BBUF(((ktv) + 1) & 1), 1); }                     \
    BARRIER();                                                          \
  }

// -------- tail-path macros (MX-fp8 e4m3, 64x128 tile, BK=128; unchanged R19) --------
#define UABUF(c) ((c) ? 8192 : 0)
#define UBBUF(c) ((c) ? 32768 : 16384)

#define USG_A(ktv, dstoff) gload16(reps8 + (size_t)(uarow0 + (t >> 3)) * 1024 + \
                                       (ktv) * 128 + (((t & 7) ^ ((t >> 3) & 7)) << 4), \
                                   smem + (dstoff) + (size_t)t * 16)
#define USG_B(ii, ktv, dstoff) gload16(reps8 + (size_t)(ubrow0 + (ii) * 64 + (t >> 3)) * 1024 + \
                                       (ktv) * 128 + (((t & 7) ^ ((t >> 3) & 7)) << 4), \
                                   smem + (dstoff) + (size_t)(ii) * 8192 + (size_t)t * 16)

#define UREAD_A(bufoff) do {                                                          \
    i32x4 a0l = *(const i32x4*)(smem + (bufoff) + uarow * 128 + off0);                \
    i32x4 a0h = *(const i32x4*)(smem + (bufoff) + uarow * 128 + off1);                \
    i32x4 a1l = *(const i32x4*)(smem + (bufoff) + (uarow + 16) * 128 + off0);         \
    i32x4 a1h = *(const i32x4*)(smem + (bufoff) + (uarow + 16) * 128 + off1);         \
    ua[0] = __builtin_shufflevector(a0l, a0h, 0, 1, 2, 3, 4, 5, 6, 7);                \
    ua[1] = __builtin_shufflevector(a1l, a1h, 0, 1, 2, 3, 4, 5, 6, 7);                \
  } while (0)

#define UREAD_B(bufoff) do {                                                          \
    i32x4 b0l = *(const i32x4*)(smem + (bufoff) + ubrow * 128 + off0);                \
    i32x4 b0h = *(const i32x4*)(smem + (bufoff) + ubrow * 128 + off1);                \
    i32x4 b1l = *(const i32x4*)(smem + (bufoff) + (ubrow + 16) * 128 + off0);         \
    i32x4 b1h = *(const i32x4*)(smem + (bufoff) + (ubrow + 16) * 128 + off1);         \
    ub[0] = __builtin_shufflevector(b0l, b0h, 0, 1, 2, 3, 4, 5, 6, 7);                \
    ub[1] = __builtin_shufflevector(b1l, b1h, 0, 1, 2, 3, 4, 5, 6, 7);                \
  } while (0)

#define UMFMA(n)                                                        \
  __builtin_amdgcn_s_setprio(1);                                        \
  _Pragma("unroll") for (int m2 = 0; m2 < 2; m2++)                      \
    uacc[m2][n] = __builtin_amdgcn_mfma_scale_f32_16x16x128_f8f6f4(     \
        ua[m2], ub[n], uacc[m2][n], 0, 0, 0, 0x7F7F7F7F, 0, 0x7F7F7F7F);\
  __builtin_amdgcn_s_setprio(0);

#define UTILE(tv, S, R, HASW, WV)                                       \
  {                                                                     \
    UMFMA(0);                                                           \
    LGKM0();                                                            \
    BARRIER();                                                          \
    if (S) { USG_A((tv) + 2, UABUF((tv) & 1));                          \
             USG_B(0, (tv) + 2, UBBUF((tv) & 1));                       \
             USG_B(1, (tv) + 2, UBBUF((tv) & 1)); }                     \
    UMFMA(1);                                                           \
    if (HASW) { WAITV(WV); }                                            \
    BARRIER();                                                          \
    if (R) { UREAD_A(UABUF(((tv) + 1) & 1)); UREAD_B(UBBUF(((tv) + 1) & 1)); } \
  }

__global__ __launch_bounds__(512, 1) void kgemm3(const unsigned char* __restrict__ reps8,
                                                 const unsigned char* __restrict__ reps4,
                                                 float* __restrict__ partial) {
  extern __shared__ char smem[];
  const int t = threadIdx.x;
  const int l = t & 63, w = t >> 6;
  const int wr = w >> 2, wc = w & 3;          // 2 x 4 wave grid
  const int q2 = (l >> 4) & 3;

  if (blockIdx.x < 128) {
    // ================= tail path (fp8): 64x128 eighth-tiles of tiles (0,16..31) =======
    const int r7 = l & 7;
    const int off0 = ((2 * q2) ^ r7) << 4;
    const int off1 = ((2 * q2 + 1) ^ r7) << 4;
    const int b = (int)blockIdx.x;              // 0..127
    const int s = b >> 3, sub = b & 7;
    const int qr = sub >> 1;                    // 64-row chunk of rows 0..255
    const int qc = sub & 1;                     // 128-col half of the 256-col tile
    const int cbt = 16 + s;

    f32x4 uacc[2][2];
    const f32x4 zero4t = {0.f, 0.f, 0.f, 0.f};
#pragma unroll
    for (int m = 0; m < 2; m++)
#pragma unroll
      for (int n = 0; n < 2; n++) uacc[m][n] = zero4t;

    const size_t uarow0 = (size_t)qr * 64;
    const size_t ubrow0 = (size_t)cbt * 256 + (size_t)qc * 128;
    const int uarow = wr * 32 + (l & 15);
    const int ubrow = wc * 32 + (l & 15);

    USG_A(0, 0); USG_B(0, 0, 16384); USG_B(1, 0, 16384);
    USG_A(1, 8192); USG_B(0, 1, 32768); USG_B(1, 1, 32768);
    WAITV(3);
    BARRIER();

    i32x8 ua[2], ub[2];
    UREAD_A(0); UREAD_B(16384);

    UTILE(0, 1, 1, 1, 3)
    UTILE(1, 1, 1, 1, 3)
    UTILE(2, 1, 1, 1, 3)
    UTILE(3, 1, 1, 1, 3)
    UTILE(4, 1, 1, 1, 3)
    UTILE(5, 1, 1, 1, 3)
    UTILE(6, 0, 1, 1, 0)
    UTILE(7, 0, 0, 0, 0)

    float rsum[2][4];
    float csum[2];
#pragma unroll
    for (int m = 0; m < 2; m++)
#pragma unroll
      for (int j = 0; j < 4; j++) rsum[m][j] = 0.f;
    csum[0] = 0.f; csum[1] = 0.f;

#pragma unroll
    for (int m = 0; m < 2; m++)
#pragma unroll
      for (int n = 0; n < 2; n++)
#pragma unroll
        for (int j = 0; j < 4; j++) {
          const float e = exp2f(uacc[m][n][j] * EXPSCALE);
          rsum[m][j] += e;
          csum[n] += e;
        }
#pragma unroll
    for (int m = 0; m < 2; m++)
#pragma unroll
      for (int j = 0; j < 4; j++) {
        float v = rsum[m][j];
        v += __shfl_xor(v, 1); v += __shfl_xor(v, 2);
        v += __shfl_xor(v, 4); v += __shfl_xor(v, 8);
        rsum[m][j] = v;
      }
#pragma unroll
    for (int n = 0; n < 2; n++) {
      float v = csum[n];
      v += __shfl_xor(v, 16); v += __shfl_xor(v, 32);
      csum[n] = v;
    }

    const int col16 = l & 15, rgp = (l >> 4) & 3;
    float* rS = (float*)smem;            // [4 wc][64 rows]
    float* cS = ((float*)smem) + 256;    // [2 wr][128 cols]
    if (col16 == 0) {
#pragma unroll
      for (int m = 0; m < 2; m++)
#pragma unroll
        for (int j = 0; j < 4; j++)
          rS[wc * 64 + wr * 32 + m * 16 + rgp * 4 + j] = rsum[m][j];
    }
    if (rgp == 0) {
#pragma unroll
      for (int n = 0; n < 2; n++)
        cS[wr * 128 + wc * 32 + n * 16 + col16] = csum[n];
    }
    __syncthreads();
    if (t < 64) {
      const float rs = rS[t] + rS[64 + t] + rS[128 + t] + rS[192 + t];
      partial[(size_t)(cbt * 2 + qc) * N2 + qr * 64 + t] = rs;
    }
    if (t < 128) {
      const float cs = cS[t] + cS[128 + t];
      partial[(size_t)(64 + qr) * N2 + cbt * 256 + qc * 128 + t] = cs;
    }
    return;
  }

  // ================= main path: 256x256 MX-fp4 tiles =================================
  int bid = (int)blockIdx.x - 128;
  bid = (bid & 7) * 64 + (bid >> 3);   // XCD swizzle (512 = 8*64, bijective)
  int rb, cb;
  if (bid < 16) {
    rb = 0; cb = bid;
  } else {
    int rem = bid - 16;
    rb = 1;
    while (rem >= NTB - rb) { rem -= NTB - rb; rb++; }
    cb = rb + rem;
  }

  f32x4 acc[8][4];
  const f32x4 zero4 = {0.f, 0.f, 0.f, 0.f};
#pragma unroll
  for (int m = 0; m < 8; m++)
#pragma unroll
    for (int n = 0; n < 4; n++) acc[m][n] = zero4;

  const size_t arow0 = (size_t)rb * 256;
  const size_t brow0 = (size_t)cb * 256;

  const int arow = wr * 128 + (l & 15);
  const int brow = wc * 64 + (l & 15);
  const int lswz = ((l & 15) >> 1) & 3;       // == (arow>>1)&3 == (brow>>1)&3
  const int off4 = ((q2 ^ lswz) << 4);
  const int aaddr = arow * 64 + off4;
  const int baddr = brow * 64 + off4;

  // ---- prologue: B(0), A(0), B(1); retire B(0)+A(0); preload tile-0 ph1 ops ----
  SG_B(0, 0, smem + 32768); SG_B(1, 0, smem + 32768);
  SG_A(0, 0, smem); SG_A(1, 0, smem);
  SG_B(0, 1, smem + 49152); SG_B(1, 1, smem + 49152);
  WAITV(2);
  BARRIER();

  i32x8 afp[2], bfp[4];
  READ_A2(0, 0);
  READ_B2(32768, 0);
  READ_B2(32768, 1);

  DO_TILE(0, 1, 1, 1, 1, 2)
  DO_TILE(1, 1, 1, 1, 1, 2)
  DO_TILE(2, 1, 1, 1, 1, 2)
  DO_TILE(3, 1, 1, 1, 1, 2)
  DO_TILE(4, 1, 1, 1, 1, 2)
  DO_TILE(5, 1, 1, 1, 1, 2)
  DO_TILE(6, 1, 0, 1, 1, 0)
  DO_TILE(7, 0, 0, 0, 0, 0)

  // -------- epilogue: exp + diagonal mask + row/col partial sums --------
  float rsum[8][4];
  float csum[4];
#pragma unroll
  for (int m = 0; m < 8; m++)
#pragma unroll
    for (int j = 0; j < 4; j++) rsum[m][j] = 0.f;
#pragma unroll
  for (int n = 0; n < 4; n++) csum[n] = 0.f;

  const int col16 = l & 15, rgp = (l >> 4) & 3;
  const bool diag = (rb == cb);
  const int growbase = wr * 128 + rgp * 4;
  const int gcolbase = wc * 64 + col16;
#pragma unroll
  for (int m = 0; m < 8; m++) {
#pragma unroll
    for (int n = 0; n < 4; n++) {
#pragma unroll
      for (int j = 0; j < 4; j++) {
        const float e = (diag && (growbase + m * 16 + j) == (gcolbase + n * 16))
                            ? 0.f
                            : exp2f(acc[m][n][j] * EXPSCALE);
        rsum[m][j] += e;
        csum[n] += e;
      }
    }
  }
#pragma unroll
  for (int m = 0; m < 8; m++)
#pragma unroll
    for (int j = 0; j < 4; j++) {
      float v = rsum[m][j];
      v += __shfl_xor(v, 1); v += __shfl_xor(v, 2);
      v += __shfl_xor(v, 4); v += __shfl_xor(v, 8);
      rsum[m][j] = v;
    }
#pragma unroll
  for (int n = 0; n < 4; n++) {
    float v = csum[n];
    v += __shfl_xor(v, 16); v += __shfl_xor(v, 32);
    csum[n] = v;
  }

  __syncthreads();   // all waves done with LDS tiles before reuse as reduction scratch
  float* rS = (float*)smem;            // [4 wc][256 rows]
  float* cS = ((float*)smem) + 1024;   // [2 wr][256 cols]
  if (col16 == 0) {
#pragma unroll
    for (int m = 0; m < 8; m++)
#pragma unroll
      for (int j = 0; j < 4; j++)
        rS[wc * 256 + wr * 128 + m * 16 + rgp * 4 + j] = rsum[m][j];
  }
  if (rgp == 0) {
#pragma unroll
    for (int n = 0; n < 4; n++)
      cS[wr * 256 + wc * 64 + n * 16 + col16] = csum[n];
  }
  __syncthreads();
  // partial layout: [68 col-blocks of 128][8192 rows]
  if (t < 256) {
    const float rs_lo = rS[t] + rS[256 + t];
    const float rs_hi = rS[512 + t] + rS[768 + t];
    partial[(size_t)(cb * 2) * N2 + rb * 256 + t] = rs_lo;
    partial[(size_t)(cb * 2 + 1) * N2 + rb * 256 + t] = rs_hi;
    if (!diag) {
      partial[(size_t)(rb * 2) * N2 + cb * 256 + t] = cS[t];
      partial[(size_t)(rb * 2 + 1) * N2 + cb * 256 + t] = cS[256 + t];
    }
  }
}

// ---------------- Kernel C: per-row denom + fused final scalar (last-block) ---------------
__device__ inline float blockReduce(float v, float* sred) {
#pragma unroll
  for (int o = 32; o > 0; o >>= 1) v += __shfl_xor(v, o);
  const int lane = threadIdx.x & 63, wid = threadIdx.x >> 6;
  if (lane == 0) sred[wid] = v;
  __syncthreads();
  v = sred[0] + sred[1] + sred[2] + sred[3];
  __syncthreads();
  return v;
}

__global__ __launch_bounds__(256) void kred1(const float* __restrict__ partial,
                                             const float* __restrict__ pos,
                                             float* __restrict__ bsum,
                                             int* __restrict__ cnt,
                                             float* __restrict__ out) {
  const int r = blockIdx.x * 256 + threadIdx.x;
  float d = 0.f;
#pragma unroll 8
  for (int cbx = 0; cbx < 64; ++cbx) d += partial[(size_t)cbx * N2 + r];
  if (blockIdx.x >= 16) {   // rows >= 4096: add tail colsum slots 64..67
#pragma unroll
    for (int cbx = 64; cbx < 68; ++cbx) d += partial[(size_t)cbx * N2 + r];
  }
  float v = logf(d);
  __shared__ float sred[4];
  __shared__ int lastFlag;
  v = blockReduce(v, sred);
  if (threadIdx.x == 0) {
    bsum[blockIdx.x] = v;
    __threadfence();
    lastFlag = (atomicAdd(cnt, 1) == 31);
  }
  __syncthreads();
  if (!lastFlag) return;
  __threadfence();
  float s = (threadIdx.x < 32) ? ((volatile float*)bsum)[threadIdx.x] : 0.f;
  float p = 0.f;
  for (int k = threadIdx.x; k < BSZ; k += 256) p += pos[k];
  s = blockReduce(s, sred);
  p = blockReduce(p, sred);
  if (threadIdx.x == 0) out[0] = (s - 2.0f * p / TEMPV) / (float)N2;
}

extern "C" void kernel_launch(void* const* d_in, const int* in_sizes, int n_in,
                              void* d_out, int out_size, void* d_ws, size_t ws_size,
                              hipStream_t stream) {
  const float* ei = (const float*)d_in[0];
  const float* ej = (const float*)d_in[1];
  char* ws = (char*)d_ws;
  unsigned char* reps8 = (unsigned char*)ws;                           // 8 MB fp8 [8192][1024]
  unsigned char* reps4 = (unsigned char*)(ws + (size_t)8 * 1024 * 1024);  // 4 MB fp4 [8192][512]
  float* partial = (float*)(ws + (size_t)12 * 1024 * 1024);            // 2.13 MB [68][8192]
  float* pos = (float*)(ws + (size_t)12 * 1024 * 1024 + 2304 * 1024);  // 16 KB [4096]
  float* bsum = (float*)(ws + (size_t)12 * 1024 * 1024 + 2304 * 1024 + 16384); // 128 B
  int* cnt = (int*)(ws + (size_t)12 * 1024 * 1024 + 2304 * 1024 + 16384 + 256);

  (void)hipFuncSetAttribute((const void*)kgemm3,
                            hipFuncAttributeMaxDynamicSharedMemorySize, 65536);

  knorm<<<BSZ, 256, 0, stream>>>(ei, ej, reps8, reps4, pos, cnt);
  kgemm3<<<640, 512, 65536, stream>>>(reps8, reps4, partial);
  kred1<<<32, 256, 0, stream>>>(partial, pos, bsum, cnt, (float*)d_out);
}

// Round 21
// 58.295 us; speedup vs baseline: 1.1913x; 1.0572x over previous
//
#include <hip/hip_runtime.h>

#define BSZ 4096
#define D 1024
#define N2 8192
#define TEMPV 0.5f
// exp(x/T) = exp2(x * log2(e)/T)
#define EXPSCALE 2.8853900817779268f
#define NTB 32      // 8192 / 256 tiles per dim

typedef __attribute__((ext_vector_type(4))) float f32x4;
typedef __attribute__((ext_vector_type(4))) int i32x4;
typedef __attribute__((ext_vector_type(8))) int i32x8;

// float (pre-scaled by 32) -> fp4 e2m1 code, nearest; code==bit pattern
__device__ inline unsigned int f2e2m1(float y) {
  const float a = fabsf(y);
  unsigned int c = (unsigned int)(a > 0.25f) + (unsigned int)(a > 0.75f) +
                   (unsigned int)(a > 1.25f) + (unsigned int)(a > 1.75f) +
                   (unsigned int)(a > 2.5f) + (unsigned int)(a > 3.5f) +
                   (unsigned int)(a > 5.0f);
  return c | ((__float_as_uint(y) >> 28) & 8u);
}

__device__ inline void gload16(const void* g, void* l) {
  __builtin_amdgcn_global_load_lds(
      (const __attribute__((address_space(1))) void*)g,
      (__attribute__((address_space(3))) void*)l, 16, 0, 0);
}

// ---------------- Kernel A: L2-normalize rows, emit fp4 reps + pos dot ------------------
__global__ __launch_bounds__(256) void knorm(const float* __restrict__ ei,
                                             const float* __restrict__ ej,
                                             unsigned char* __restrict__ reps4,
                                             float* __restrict__ pos,
                                             int* __restrict__ cnt) {
  const int r = blockIdx.x;
  const int t = threadIdx.x;
  if (r == 0 && t == 0) *cnt = 0;   // reset done-counter for fused kred (every call)
  const float4 vi = ((const float4*)(ei + (size_t)r * D))[t];
  const float4 vj = ((const float4*)(ej + (size_t)r * D))[t];
  float ssi = vi.x * vi.x + vi.y * vi.y + vi.z * vi.z + vi.w * vi.w;
  float ssj = vj.x * vj.x + vj.y * vj.y + vj.z * vj.z + vj.w * vj.w;
  float sij = vi.x * vj.x + vi.y * vj.y + vi.z * vj.z + vi.w * vj.w;
#pragma unroll
  for (int o = 32; o > 0; o >>= 1) {
    ssi += __shfl_xor(ssi, o);
    ssj += __shfl_xor(ssj, o);
    sij += __shfl_xor(sij, o);
  }
  __shared__ float red[12];
  const int lane = t & 63, wid = t >> 6;
  if (lane == 0) { red[wid * 3] = ssi; red[wid * 3 + 1] = ssj; red[wid * 3 + 2] = sij; }
  __syncthreads();
  ssi = red[0] + red[3] + red[6] + red[9];
  ssj = red[1] + red[4] + red[7] + red[10];
  sij = red[2] + red[5] + red[8] + red[11];
  const float inv_i = rsqrtf(fmaxf(ssi, 1e-24f)) * 32.f;
  const float inv_j = rsqrtf(fmaxf(ssj, 1e-24f)) * 32.f;
  const unsigned int qi = f2e2m1(vi.x * inv_i) | (f2e2m1(vi.y * inv_i) << 4) |
                          (f2e2m1(vi.z * inv_i) << 8) | (f2e2m1(vi.w * inv_i) << 12);
  const unsigned int qj = f2e2m1(vj.x * inv_j) | (f2e2m1(vj.y * inv_j) << 4) |
                          (f2e2m1(vj.z * inv_j) << 8) | (f2e2m1(vj.w * inv_j) << 12);
  *(unsigned short*)(reps4 + (size_t)r * 512 + t * 2) = (unsigned short)qi;
  *(unsigned short*)(reps4 + (size_t)(BSZ + r) * 512 + t * 2) = (unsigned short)qj;
  if (t == 0) pos[r] = sij * inv_i * inv_j * (1.f / 1024.f);
}

// ======================= shared asm helpers =======================
#define BARRIER() do { __builtin_amdgcn_s_barrier(); asm volatile("" ::: "memory"); } while (0)
#define STR2(x) #x
#define WAITV(n) asm volatile("s_waitcnt vmcnt(" STR2(n) ")" ::: "memory")

// ---------------- Kernel B (merged): fp4 tails FIRST (0..63), fp4 mains (64..575) -------
// Main: 256x256 MX-fp4 tile, BK=128 (rows = 64B), 8 waves (2Mx4N), wave tile 128x64.
// LDS: A dbuf @0/@16384, B dbuf @32768/@49152. Swizzle: 16B chunk c at c ^ ((row>>1)&3).
// fp4 operand = one b128/lane DUPLICATED into both operand halves (FMT=4-safe).
// Scales 0x7A = 2^-5 on both sides (values pre-scaled by 32). R20 ledger.
#define SG_A(ii, ktv, dst) gload16(reps4 + (size_t)(arow0 + (ii) * 128 + (t >> 2)) * 512 + \
                                       (ktv) * 64 + (((t & 3) ^ ((t >> 3) & 3)) << 4),     \
                                   (dst) + (size_t)(ii) * 8192 + (size_t)t * 16)
#define SG_B(ii, ktv, dst) gload16(reps4 + (size_t)(brow0 + (ii) * 128 + (t >> 2)) * 512 + \
                                       (ktv) * 64 + (((t & 3) ^ ((t >> 3) & 3)) << 4),     \
                                   (dst) + (size_t)(ii) * 8192 + (size_t)t * 16)

#define ABUF(c) ((c) ? 16384 : 0)
#define BBUF(c) ((c) ? 49152 : 32768)

#define READ_A2(bufoff, p) do {                                                       \
    i32x4 a0 = *(const i32x4*)(smem + (bufoff) + aaddr + ((p) * 2) * 1024);           \
    i32x4 a1 = *(const i32x4*)(smem + (bufoff) + aaddr + ((p) * 2 + 1) * 1024);       \
    afp[0] = __builtin_shufflevector(a0, a0, 0, 1, 2, 3, 0, 1, 2, 3);                 \
    afp[1] = __builtin_shufflevector(a1, a1, 0, 1, 2, 3, 0, 1, 2, 3);                 \
  } while (0)

#define READ_B2(bufoff, n) do {                                                       \
    i32x4 b0 = *(const i32x4*)(smem + (bufoff) + baddr + (n) * 1024);                 \
    bfp[n] = __builtin_shufflevector(b0, b0, 0, 1, 2, 3, 0, 1, 2, 3);                 \
  } while (0)

#define MFMA_P(p)                                                       \
  __builtin_amdgcn_s_setprio(1);                                        \
  _Pragma("unroll") for (int nh = 0; nh < 2; nh++)                      \
  _Pragma("unroll") for (int m2 = 0; m2 < 2; m2++)                      \
  _Pragma("unroll") for (int nn = 0; nn < 2; nn++) {                    \
    const int n_ = nh * 2 + nn;                                         \
    acc[2 * (p) + m2][n_] = __builtin_amdgcn_mfma_scale_f32_16x16x128_f8f6f4( \
        afp[m2], bfp[n_], acc[2 * (p) + m2][n_],                        \
        4, 4, 0, 0x7A7A7A7A, 0, 0x7A7A7A7A);                            \
  }                                                                     \
  __builtin_amdgcn_s_setprio(0);

#define DO_TILE(ktv, SA, SB, RDN, HASW, WV)                             \
  {                                                                     \
    READ_B2(BBUF((ktv) & 1), 2); READ_B2(BBUF((ktv) & 1), 3);           \
    MFMA_P(0);                                                          \
    READ_A2(ABUF((ktv) & 1), 1);                                        \
    if (SA) { SG_A(0, (ktv) + 1, smem + ABUF(((ktv) + 1) & 1));         \
              SG_A(1, (ktv) + 1, smem + ABUF(((ktv) + 1) & 1)); }       \
    BARRIER();                                                          \
    MFMA_P(1);                                                          \
    READ_A2(ABUF((ktv) & 1), 2);                                        \
    BARRIER();                                                          \
    MFMA_P(2);                                                          \
    READ_A2(ABUF((ktv) & 1), 3);                                        \
    if (SB) { SG_B(0, (ktv) + 2, smem + BBUF((ktv) & 1));               \
              SG_B(1, (ktv) + 2, smem + BBUF((ktv) & 1)); }             \
    if (HASW) { WAITV(WV); }                                            \
    BARRIER();                                                          \
    MFMA_P(3);                                                          \
    if (RDN) { READ_A2(ABUF(((ktv) + 1) & 1), 0);                       \
               READ_B2(BBUF(((ktv) + 1) & 1), 0);                       \
               READ_B2(BBUF(((ktv) + 1) & 1), 1); }                     \
    BARRIER();                                                          \
  }

// -------- tail-path macros (MX-fp4, 128x128 quarter-tile, BK=128) --------
// LDS: A dbuf @0/@8192, B dbuf @16384/@24576 (8 KB each = 128 rows x 64 B).
// Per-thread ledger: 1 SG_A@ph1(t+1), 1 SG_B@ph3(t+2); WAITV(1)@ph3 retires
// B(t+1)+A(t+1); t6 WAITV(0); prologue B(0),A(0),B(1) + WAITV(1).
#define TABUF(c) ((c) ? 8192 : 0)
#define TBBUF(c) ((c) ? 24576 : 16384)

#define TSG_A(ktv, dstoff) gload16(reps4 + (size_t)(tarow0 + (t >> 2)) * 512 + \
                                       (ktv) * 64 + (((t & 3) ^ ((t >> 3) & 3)) << 4), \
                                   smem + (dstoff) + (size_t)t * 16)
#define TSG_B(ktv, dstoff) gload16(reps4 + (size_t)(tbrow0 + (t >> 2)) * 512 + \
                                       (ktv) * 64 + (((t & 3) ^ ((t >> 3) & 3)) << 4), \
                                   smem + (dstoff) + (size_t)t * 16)

#define READ_TA(bufoff, m, dst) do {                                                  \
    i32x4 a0 = *(const i32x4*)(smem + (bufoff) + taaddr + (m) * 1024);                \
    dst = __builtin_shufflevector(a0, a0, 0, 1, 2, 3, 0, 1, 2, 3);                    \
  } while (0)

#define READ_TB(bufoff, n) do {                                                       \
    i32x4 b0 = *(const i32x4*)(smem + (bufoff) + tbaddr + (n) * 1024);                \
    tbfp[n] = __builtin_shufflevector(b0, b0, 0, 1, 2, 3, 0, 1, 2, 3);                \
  } while (0)

#define TMFMA(m, areg)                                                  \
  __builtin_amdgcn_s_setprio(1);                                        \
  _Pragma("unroll") for (int n_ = 0; n_ < 2; n_++)                      \
    tacc[m][n_] = __builtin_amdgcn_mfma_scale_f32_16x16x128_f8f6f4(     \
        areg, tbfp[n_], tacc[m][n_], 4, 4, 0, 0x7A7A7A7A, 0, 0x7A7A7A7A); \
  __builtin_amdgcn_s_setprio(0);

#define TTILE(ktv, SA, SB, RDN, HASW, WV)                               \
  {                                                                     \
    READ_TB(TBBUF((ktv) & 1), 1);                                       \
    TMFMA(0, tafp[0]);                                                  \
    READ_TA(TABUF((ktv) & 1), 1, tafp[1]);                              \
    if (SA) TSG_A((ktv) + 1, TABUF(((ktv) + 1) & 1));                   \
    BARRIER();                                                          \
    TMFMA(1, tafp[1]);                                                  \
    READ_TA(TABUF((ktv) & 1), 2, tafp[0]);                              \
    BARRIER();                                                          \
    TMFMA(2, tafp[0]);                                                  \
    READ_TA(TABUF((ktv) & 1), 3, tafp[1]);                              \
    if (SB) TSG_B((ktv) + 2, TBBUF((ktv) & 1));                         \
    if (HASW) { WAITV(WV); }                                            \
    BARRIER();                                                          \
    TMFMA(3, tafp[1]);                                                  \
    if (RDN) { READ_TA(TABUF(((ktv) + 1) & 1), 0, tafp[0]);             \
               READ_TB(TBBUF(((ktv) + 1) & 1), 0); }                    \
    BARRIER();                                                          \
  }

__global__ __launch_bounds__(512, 1) void kgemm3(const unsigned char* __restrict__ reps4,
                                                 float* __restrict__ partial) {
  extern __shared__ char smem[];
  const int t = threadIdx.x;
  const int l = t & 63, w = t >> 6;
  const int wr = w >> 2, wc = w & 3;          // 2 x 4 wave grid
  const int q2 = (l >> 4) & 3;
  const int lswz = ((l & 15) >> 1) & 3;       // == (row>>1)&3 for all row bases used
  const int off4 = ((q2 ^ lswz) << 4);

  if (blockIdx.x < 64) {
    // ===== tail path (fp4): 128x128 quarter-tiles of excluded tiles (0, 16..31) =======
    const int b = (int)blockIdx.x;              // 0..63
    const int s = b >> 2, quad = b & 3;
    const int qr = quad >> 1, qc = quad & 1;
    const int cbt = 16 + s;

    f32x4 tacc[4][2];
    const f32x4 zero4t = {0.f, 0.f, 0.f, 0.f};
#pragma unroll
    for (int m = 0; m < 4; m++)
#pragma unroll
      for (int n = 0; n < 2; n++) tacc[m][n] = zero4t;

    const size_t tarow0 = (size_t)qr * 128;                     // rows 0..255
    const size_t tbrow0 = (size_t)cbt * 256 + (size_t)qc * 128; // cols >= 4096
    const int taaddr = (wr * 64 + (l & 15)) * 64 + off4;        // + m*1024
    const int tbaddr = (wc * 32 + (l & 15)) * 64 + off4;        // + n*1024

    // prologue: B(0), A(0), B(1); retire B(0)+A(0); preload tile-0 ops
    TSG_B(0, 16384);
    TSG_A(0, 0);
    TSG_B(1, 24576);
    WAITV(1);
    BARRIER();

    i32x8 tafp[2], tbfp[2];
    READ_TA(0, 0, tafp[0]);
    READ_TB(16384, 0);

    TTILE(0, 1, 1, 1, 1, 1)
    TTILE(1, 1, 1, 1, 1, 1)
    TTILE(2, 1, 1, 1, 1, 1)
    TTILE(3, 1, 1, 1, 1, 1)
    TTILE(4, 1, 1, 1, 1, 1)
    TTILE(5, 1, 1, 1, 1, 1)
    TTILE(6, 1, 0, 1, 1, 0)
    TTILE(7, 0, 0, 0, 0, 0)

    // epilogue (no diagonal: rows < 256, cols >= 4096)
    float rsum[4][4];
    float csum[2];
#pragma unroll
    for (int m = 0; m < 4; m++)
#pragma unroll
      for (int j = 0; j < 4; j++) rsum[m][j] = 0.f;
    csum[0] = 0.f; csum[1] = 0.f;

#pragma unroll
    for (int m = 0; m < 4; m++)
#pragma unroll
      for (int n = 0; n < 2; n++)
#pragma unroll
        for (int j = 0; j < 4; j++) {
          const float e = exp2f(tacc[m][n][j] * EXPSCALE);
          rsum[m][j] += e;
          csum[n] += e;
        }
#pragma unroll
    for (int m = 0; m < 4; m++)
#pragma unroll
      for (int j = 0; j < 4; j++) {
        float v = rsum[m][j];
        v += __shfl_xor(v, 1); v += __shfl_xor(v, 2);
        v += __shfl_xor(v, 4); v += __shfl_xor(v, 8);
        rsum[m][j] = v;
      }
#pragma unroll
    for (int n = 0; n < 2; n++) {
      float v = csum[n];
      v += __shfl_xor(v, 16); v += __shfl_xor(v, 32);
      csum[n] = v;
    }

    const int col16 = l & 15, rgp = (l >> 4) & 3;
    __syncthreads();
    float* rS = (float*)smem;            // [4 wc][128 rows]
    float* cS = ((float*)smem) + 512;    // [2 wr][128 cols]
    if (col16 == 0) {
#pragma unroll
      for (int m = 0; m < 4; m++)
#pragma unroll
        for (int j = 0; j < 4; j++)
          rS[wc * 128 + wr * 64 + m * 16 + rgp * 4 + j] = rsum[m][j];
    }
    if (rgp == 0) {
#pragma unroll
      for (int n = 0; n < 2; n++)
        cS[wr * 128 + wc * 32 + n * 16 + col16] = csum[n];
    }
    __syncthreads();
    if (t < 128) {
      const float rs = rS[t] + rS[128 + t] + rS[256 + t] + rS[384 + t];
      partial[(size_t)(cbt * 2 + qc) * N2 + qr * 128 + t] = rs;
      const float cs = cS[t] + cS[128 + t];
      partial[(size_t)(64 + qr) * N2 + cbt * 256 + qc * 128 + t] = cs;
    }
    return;
  }

  // ================= main path: 256x256 MX-fp4 tiles (R20 verbatim) ==================
  int bid = (int)blockIdx.x - 64;
  bid = (bid & 7) * 64 + (bid >> 3);   // XCD swizzle (512 = 8*64, bijective)
  int rb, cb;
  if (bid < 16) {
    rb = 0; cb = bid;
  } else {
    int rem = bid - 16;
    rb = 1;
    while (rem >= NTB - rb) { rem -= NTB - rb; rb++; }
    cb = rb + rem;
  }

  f32x4 acc[8][4];
  const f32x4 zero4 = {0.f, 0.f, 0.f, 0.f};
#pragma unroll
  for (int m = 0; m < 8; m++)
#pragma unroll
    for (int n = 0; n < 4; n++) acc[m][n] = zero4;

  const size_t arow0 = (size_t)rb * 256;
  const size_t brow0 = (size_t)cb * 256;

  const int arow = wr * 128 + (l & 15);
  const int brow = wc * 64 + (l & 15);
  const int aaddr = arow * 64 + off4;
  const int baddr = brow * 64 + off4;

  // ---- prologue: B(0), A(0), B(1); retire B(0)+A(0); preload tile-0 ph1 ops ----
  SG_B(0, 0, smem + 32768); SG_B(1, 0, smem + 32768);
  SG_A(0, 0, smem); SG_A(1, 0, smem);
  SG_B(0, 1, smem + 49152); SG_B(1, 1, smem + 49152);
  WAITV(2);
  BARRIER();

  i32x8 afp[2], bfp[4];
  READ_A2(0, 0);
  READ_B2(32768, 0);
  READ_B2(32768, 1);

  DO_TILE(0, 1, 1, 1, 1, 2)
  DO_TILE(1, 1, 1, 1, 1, 2)
  DO_TILE(2, 1, 1, 1, 1, 2)
  DO_TILE(3, 1, 1, 1, 1, 2)
  DO_TILE(4, 1, 1, 1, 1, 2)
  DO_TILE(5, 1, 1, 1, 1, 2)
  DO_TILE(6, 1, 0, 1, 1, 0)
  DO_TILE(7, 0, 0, 0, 0, 0)

  // -------- epilogue: exp + diagonal mask + row/col partial sums --------
  float rsum[8][4];
  float csum[4];
#pragma unroll
  for (int m = 0; m < 8; m++)
#pragma unroll
    for (int j = 0; j < 4; j++) rsum[m][j] = 0.f;
#pragma unroll
  for (int n = 0; n < 4; n++) csum[n] = 0.f;

  const int col16 = l & 15, rgp = (l >> 4) & 3;
  const bool diag = (rb == cb);
  const int growbase = wr * 128 + rgp * 4;
  const int gcolbase = wc * 64 + col16;
#pragma unroll
  for (int m = 0; m < 8; m++) {
#pragma unroll
    for (int n = 0; n < 4; n++) {
#pragma unroll
      for (int j = 0; j < 4; j++) {
        const float e = (diag && (growbase + m * 16 + j) == (gcolbase + n * 16))
                            ? 0.f
                            : exp2f(acc[m][n][j] * EXPSCALE);
        rsum[m][j] += e;
        csum[n] += e;
      }
    }
  }
#pragma unroll
  for (int m = 0; m < 8; m++)
#pragma unroll
    for (int j = 0; j < 4; j++) {
      float v = rsum[m][j];
      v += __shfl_xor(v, 1); v += __shfl_xor(v, 2);
      v += __shfl_xor(v, 4); v += __shfl_xor(v, 8);
      rsum[m][j] = v;
    }
#pragma unroll
  for (int n = 0; n < 4; n++) {
    float v = csum[n];
    v += __shfl_xor(v, 16); v += __shfl_xor(v, 32);
    csum[n] = v;
  }

  __syncthreads();   // all waves done with LDS tiles before reuse as reduction scratch
  float* rS = (float*)smem;            // [4 wc][256 rows]
  float* cS = ((float*)smem) + 1024;   // [2 wr][256 cols]
  if (col16 == 0) {
#pragma unroll
    for (int m = 0; m < 8; m++)
#pragma unroll
      for (int j = 0; j < 4; j++)
        rS[wc * 256 + wr * 128 + m * 16 + rgp * 4 + j] = rsum[m][j];
  }
  if (rgp == 0) {
#pragma unroll
    for (int n = 0; n < 4; n++)
      cS[wr * 256 + wc * 64 + n * 16 + col16] = csum[n];
  }
  __syncthreads();
  // partial layout: [66 col-blocks of 128][8192 rows]
  if (t < 256) {
    const float rs_lo = rS[t] + rS[256 + t];
    const float rs_hi = rS[512 + t] + rS[768 + t];
    partial[(size_t)(cb * 2) * N2 + rb * 256 + t] = rs_lo;
    partial[(size_t)(cb * 2 + 1) * N2 + rb * 256 + t] = rs_hi;
    if (!diag) {
      partial[(size_t)(rb * 2) * N2 + cb * 256 + t] = cS[t];
      partial[(size_t)(rb * 2 + 1) * N2 + cb * 256 + t] = cS[256 + t];
    }
  }
}

// ---------------- Kernel C: per-row denom + fused final scalar (last-block) ---------------
__device__ inline float blockReduce(float v, float* sred) {
#pragma unroll
  for (int o = 32; o > 0; o >>= 1) v += __shfl_xor(v, o);
  const int lane = threadIdx.x & 63, wid = threadIdx.x >> 6;
  if (lane == 0) sred[wid] = v;
  __syncthreads();
  v = sred[0] + sred[1] + sred[2] + sred[3];
  __syncthreads();
  return v;
}

__global__ __launch_bounds__(256) void kred1(const float* __restrict__ partial,
                                             const float* __restrict__ pos,
                                             float* __restrict__ bsum,
                                             int* __restrict__ cnt,
                                             float* __restrict__ out) {
  const int r = blockIdx.x * 256 + threadIdx.x;
  float d = 0.f;
#pragma unroll 8
  for (int cbx = 0; cbx < 64; ++cbx) d += partial[(size_t)cbx * N2 + r];
  if (blockIdx.x >= 16) {   // rows >= 4096: add tail colsum slots 64..65
    d += partial[(size_t)64 * N2 + r];
    d += partial[(size_t)65 * N2 + r];
  }
  float v = logf(d);
  __shared__ float sred[4];
  __shared__ int lastFlag;
  v = blockReduce(v, sred);
  if (threadIdx.x == 0) {
    bsum[blockIdx.x] = v;
    __threadfence();
    lastFlag = (atomicAdd(cnt, 1) == 31);
  }
  __syncthreads();
  if (!lastFlag) return;
  __threadfence();
  float s = (threadIdx.x < 32) ? ((volatile float*)bsum)[threadIdx.x] : 0.f;
  float p = 0.f;
  for (int k = threadIdx.x; k < BSZ; k += 256) p += pos[k];
  s = blockReduce(s, sred);
  p = blockReduce(p, sred);
  if (threadIdx.x == 0) out[0] = (s - 2.0f * p / TEMPV) / (float)N2;
}

extern "C" void kernel_launch(void* const* d_in, const int* in_sizes, int n_in,
                              void* d_out, int out_size, void* d_ws, size_t ws_size,
                              hipStream_t stream) {
  const float* ei = (const float*)d_in[0];
  const float* ej = (const float*)d_in[1];
  char* ws = (char*)d_ws;
  unsigned char* reps4 = (unsigned char*)ws;                           // 4 MB fp4 [8192][512]
  float* partial = (float*)(ws + (size_t)4 * 1024 * 1024);             // 2.06 MB [66][8192]
  float* pos = (float*)(ws + (size_t)4 * 1024 * 1024 + 2176 * 1024);   // 16 KB [4096]
  float* bsum = (float*)(ws + (size_t)4 * 1024 * 1024 + 2176 * 1024 + 16384); // 128 B
  int* cnt = (int*)(ws + (size_t)4 * 1024 * 1024 + 2176 * 1024 + 16384 + 256);

  (void)hipFuncSetAttribute((const void*)kgemm3,
                            hipFuncAttributeMaxDynamicSharedMemorySize, 65536);

  knorm<<<BSZ, 256, 0, stream>>>(ei, ej, reps4, pos, cnt);
  kgemm3<<<576, 512, 65536, stream>>>(reps4, partial);
  kred1<<<32, 256, 0, stream>>>(partial, pos, bsum, cnt, (float*)d_out);
}